// Round 14
// baseline (534.772 us; speedup 1.0000x reference)
//
#include <hip/hip_runtime.h>
#include <hip/hip_bf16.h>
#include <math.h>

#define B_ 4
#define S_ 512
#define DM_ 768
#define L_ 2
#define DI_ 1536
#define DS_ 16
#define KC_ 4
#define DTR_ 48
#define NSEG 32
#define TS 16

typedef __hip_bfloat16 bf16;
typedef __attribute__((ext_vector_type(8))) short short8;
typedef __attribute__((ext_vector_type(4))) float f32x4;

#define GLDS16(g, l) __builtin_amdgcn_global_load_lds( \
    (const __attribute__((address_space(1))) void*)(g), \
    (__attribute__((address_space(3))) void*)(l), 16, 0, 0)

// ---------------- elementwise / small kernels ----------------

// fused embed + LN1: one block per row (b*S+s)
__global__ __launch_bounds__(256)
void k_embed_ln(const float* __restrict__ x, const float* __restrict__ w_in,
                const float* __restrict__ b_in, const float* __restrict__ pe,
                const float* __restrict__ lw, const float* __restrict__ lb,
                float* __restrict__ h, bf16* __restrict__ xout) {
  __shared__ float red1[4], red2[4];
  __shared__ float s_mu, s_rstd;
  int row = blockIdx.x;
  int s = row % S_;
  float xv = x[row];
  float v[3];
  float s1 = 0.f, s2 = 0.f;
#pragma unroll
  for (int j = 0; j < 3; ++j) {
    int d = threadIdx.x + j * 256;
    float t = xv * w_in[d] + b_in[d] + pe[s * DM_ + d];
    v[j] = t;
    s1 += t; s2 += t * t;
  }
  for (int off = 32; off; off >>= 1) { s1 += __shfl_down(s1, off); s2 += __shfl_down(s2, off); }
  if ((threadIdx.x & 63) == 0) { red1[threadIdx.x >> 6] = s1; red2[threadIdx.x >> 6] = s2; }
  __syncthreads();
  if (threadIdx.x == 0) {
    float t1 = red1[0] + red1[1] + red1[2] + red1[3];
    float t2 = red2[0] + red2[1] + red2[2] + red2[3];
    float mu = t1 * (1.f / DM_);
    float var = t2 * (1.f / DM_) - mu * mu;
    s_mu = mu;
    s_rstd = rsqrtf(var + 1e-5f);
  }
  __syncthreads();
  float mu = s_mu, rstd = s_rstd;
#pragma unroll
  for (int j = 0; j < 3; ++j) {
    int d = threadIdx.x + j * 256;
    h[(size_t)row * DM_ + d] = v[j];
    xout[(size_t)row * DM_ + d] = __float2bfloat16((v[j] - mu) * rstd * lw[d] + lb[d]);
  }
}

// LayerNorm over h (which already holds residual + GEMM atomic sums).
// If bias: hnew = h + bias, write back to hout. Then xout = bf16(LN(hnew)).
__global__ __launch_bounds__(256)
void k_lnorm(const float* __restrict__ hin, const float* __restrict__ bias,
             const float* __restrict__ lw, const float* __restrict__ lb,
             float* __restrict__ hout, bf16* __restrict__ xout) {
  __shared__ float red1[4], red2[4];
  __shared__ float s_mu, s_rstd;
  int row = blockIdx.x;
  float v[3];
  float s1 = 0.f, s2 = 0.f;
#pragma unroll
  for (int j = 0; j < 3; ++j) {
    int n = threadIdx.x + j * 256;
    float s = hin[(size_t)row * DM_ + n];
    if (bias) s += bias[n];
    v[j] = s;
    s1 += s; s2 += s * s;
  }
  for (int off = 32; off; off >>= 1) { s1 += __shfl_down(s1, off); s2 += __shfl_down(s2, off); }
  if ((threadIdx.x & 63) == 0) { red1[threadIdx.x >> 6] = s1; red2[threadIdx.x >> 6] = s2; }
  __syncthreads();
  if (threadIdx.x == 0) {
    float t1 = red1[0] + red1[1] + red1[2] + red1[3];
    float t2 = red2[0] + red2[1] + red2[2] + red2[3];
    float mu = t1 * (1.f / DM_);
    float var = t2 * (1.f / DM_) - mu * mu;
    s_mu = mu;
    s_rstd = rsqrtf(var + 1e-5f);
  }
  __syncthreads();
  float mu = s_mu, rstd = s_rstd;
#pragma unroll
  for (int j = 0; j < 3; ++j) {
    int n = threadIdx.x + j * 256;
    if (bias) hout[(size_t)row * DM_ + n] = v[j];
    xout[(size_t)row * DM_ + n] = __float2bfloat16((v[j] - mu) * rstd * lw[n] + lb[n]);
  }
}

// fused split-K(2) reduce (bf16 partials) + bias + exact GELU -> bf16 (ff1 epilogue)
__global__ void k_gelred(const bf16* __restrict__ pxp, const float* __restrict__ bias,
                         bf16* __restrict__ out) {
  int idx = blockIdx.x * 256 + threadIdx.x;
  if (idx >= 2048 * 2 * DM_) return;
  int n = idx % (2 * DM_);
  float s = __bfloat162float(pxp[idx]) +
            __bfloat162float(pxp[(size_t)2048 * 2 * DM_ + idx]) + bias[n];
  s = 0.5f * s * (1.f + erff(s * 0.70710678118654752f));
  out[idx] = __float2bfloat16(s);
}

// ---------------- vectorized weight casts ----------------
typedef struct { unsigned short x, y, z, w; } us4;
__device__ __forceinline__ void cast4(const float* __restrict__ s, bf16* __restrict__ d) {
  float4 v = *(const float4*)s;
  us4 o;
  o.x = __bfloat16_as_ushort(__float2bfloat16(v.x));
  o.y = __bfloat16_as_ushort(__float2bfloat16(v.y));
  o.z = __bfloat16_as_ushort(__float2bfloat16(v.z));
  o.w = __bfloat16_as_ushort(__float2bfloat16(v.w));
  *(us4*)d = o;
}
__device__ __forceinline__ void store4z(bf16* __restrict__ d) {
  us4 o; o.x = o.y = o.z = o.w = 0;
  *(us4*)d = o;
}

// all weight casts (float4-vectorized) + A transpose (At = -exp(A_log), [l][n][DI])
__global__ void k_castall(const float* __restrict__ w_inproj, const float* __restrict__ w_outproj,
                          const float* __restrict__ ff_w1, const float* __restrict__ ff_w2,
                          const float* __restrict__ w_xproj, const float* __restrict__ w_dt,
                          const float* __restrict__ A_log,
                          bf16* __restrict__ wip, bf16* __restrict__ wop,
                          bf16* __restrict__ wf1, bf16* __restrict__ wf2,
                          bf16* __restrict__ wxp, bf16* __restrict__ wdtp,
                          float* __restrict__ At) {
  const int N0 = L_ * 2 * DI_ * DM_;
  const int N1 = L_ * DM_ * DI_;
  const int N2 = L_ * 2 * DM_ * DM_;
  const int N3 = L_ * DM_ * 2 * DM_;
  const int N4 = L_ * 128 * DI_;
  const int N5 = L_ * DI_ * 64;
  const int N6 = L_ * 16 * DI_;
  const int T4 = (N0 + N1 + N2 + N3 + N4 + N5) >> 2;
  int tid = blockIdx.x * 256 + threadIdx.x;
  int stride = gridDim.x * 256;
  for (int v = tid; v < T4; v += stride) {
    int j = v << 2;
    if (j < N0) { cast4(w_inproj + j, wip + j); continue; }
    j -= N0;
    if (j < N1) { cast4(w_outproj + j, wop + j); continue; }
    j -= N1;
    if (j < N2) { cast4(ff_w1 + j, wf1 + j); continue; }
    j -= N2;
    if (j < N3) { cast4(ff_w2 + j, wf2 + j); continue; }
    j -= N3;
    if (j < N4) {
      int col = j % DI_;
      int row = (j / DI_) & 127;
      int l = j / (128 * DI_);
      if (row < 80) cast4(&w_xproj[((size_t)l * 80 + row) * DI_ + col], wxp + j);
      else store4z(wxp + j);
      continue;
    }
    j -= N4;
    {
      int col = j & 63;
      int r = (j >> 6) % DI_;
      int l = j / (DI_ * 64);
      if (col < 48) cast4(&w_dt[((size_t)l * DI_ + r) * 48 + col], wdtp + j);
      else store4z(wdtp + j);
    }
  }
  for (int j = tid; j < N6; j += stride) {
    int d = j % DI_;
    int n = (j / DI_) & 15;
    int l = j / (16 * DI_);
    At[j] = -__expf(A_log[((size_t)l * DI_ + d) * 16 + n]);
  }
}

// depthwise causal conv (K=4) + bias + SiLU; 2 d's per thread, ushort2 loads/stores
__global__ void k_conv_silu(const bf16* __restrict__ xz, const float* __restrict__ cw,
                            const float* __restrict__ cb, bf16* __restrict__ xcb) {
  int idx = blockIdx.x * 256 + threadIdx.x;
  if (idx >= B_ * S_ * (DI_ / 2)) return;
  int d2 = idx % (DI_ / 2);
  int d = d2 * 2;
  int t = idx / (DI_ / 2);
  int s = t % S_;
  int b = t / S_;
  float a0 = cb[d], a1 = cb[d + 1];
  const bf16* base = xz + (size_t)(b * S_) * (2 * DI_) + d;
#pragma unroll
  for (int k = 0; k < KC_; ++k) {
    int ss = s - (KC_ - 1) + k;
    if (ss >= 0) {
      ushort2 v = *(const ushort2*)&base[(size_t)ss * (2 * DI_)];
      a0 = fmaf(__bfloat162float(__ushort_as_bfloat16(v.x)), cw[d * KC_ + k], a0);
      a1 = fmaf(__bfloat162float(__ushort_as_bfloat16(v.y)), cw[(d + 1) * KC_ + k], a1);
    }
  }
  float v0 = a0 / (1.f + expf(-a0));
  float v1 = a1 / (1.f + expf(-a1));
  ushort2 o;
  o.x = __bfloat16_as_ushort(__float2bfloat16(v0));
  o.y = __bfloat16_as_ushort(__float2bfloat16(v1));
  *(ushort2*)&xcb[(size_t)t * DI_ + d] = o;
}

// ---------------- segmented selective scan ----------------
// Pass A: one thread per d; u read from xcb (bf16); 16 states in VGPRs.
__global__ __launch_bounds__(256)
void k_scanA(const float* __restrict__ delta, const bf16* __restrict__ xcb,
             const float* __restrict__ bc, const float* __restrict__ At,
             const float* __restrict__ Dv,
             float* __restrict__ ylocal, float* __restrict__ cumd,
             float* __restrict__ hend) {
  int b = blockIdx.y;
  int seg = blockIdx.z;
  int d = blockIdx.x * 256 + threadIdx.x;
  int s0 = seg * TS;

  float A[16], hst[16];
#pragma unroll
  for (int n = 0; n < 16; ++n) {
    A[n] = At[(size_t)n * DI_ + d];
    hst[n] = 0.f;
  }
  float Dd = Dv[d];
  float cd = 0.f;

  const float* dp = delta + ((size_t)(b * S_ + s0)) * DI_ + d;
  const bf16* up = xcb + ((size_t)(b * S_ + s0)) * DI_ + d;
  const float* bp = bc + ((size_t)(b * S_ + s0)) * 32;
  float* yp = ylocal + ((size_t)(b * S_ + s0)) * DI_ + d;
  float* cp = cumd + ((size_t)(b * S_ + s0)) * DI_ + d;

  float dl_next = dp[0];
  float u_next = __bfloat162float(up[0]);
#pragma unroll 4
  for (int s = 0; s < TS; ++s) {
    float dl = dl_next, u = u_next;
    if (s + 1 < TS) {
      dl_next = dp[(size_t)(s + 1) * DI_];
      u_next = __bfloat162float(up[(size_t)(s + 1) * DI_]);
    }
    cd += dl;
    float dlu = dl * u;
    float y = 0.f;
#pragma unroll
    for (int n = 0; n < 16; ++n) {
      float e = __expf(dl * A[n]);
      hst[n] = fmaf(hst[n], e, dlu * bp[s * 32 + n]);
      y = fmaf(hst[n], bp[s * 32 + 16 + n], y);
    }
    yp[(size_t)s * DI_] = fmaf(u, Dd, y);
    cp[(size_t)s * DI_] = cd;
  }
  float* hp = hend + ((size_t)(b * NSEG + seg) * 16) * DI_ + d;
#pragma unroll
  for (int n = 0; n < 16; ++n) hp[(size_t)n * DI_] = hst[n];
}

__global__ void k_scanB(const float* __restrict__ hend, const float* __restrict__ cumd,
                        const float* __restrict__ At, float* __restrict__ h0seg) {
  int idx = blockIdx.x * 256 + threadIdx.x;
  if (idx >= B_ * 16 * DI_) return;
  int d = idx % DI_;
  int r = idx / DI_;
  int n = r & 15;
  int b = r >> 4;
  float A = At[(size_t)n * DI_ + d];
  float h0 = 0.f;
  for (int seg = 0; seg < NSEG; ++seg) {
    size_t o = ((size_t)(b * NSEG + seg) * 16 + n) * DI_ + d;
    h0seg[o] = h0;
    float cdt = cumd[((size_t)(b * S_ + seg * TS + TS - 1)) * DI_ + d];
    h0 = h0 * __expf(A * cdt) + hend[o];
  }
}

__global__ __launch_bounds__(256)
void k_scanC(const float* __restrict__ ylocal, const float* __restrict__ cumd,
             const float* __restrict__ bc, const float* __restrict__ At,
             const float* __restrict__ h0seg, const bf16* __restrict__ xz,
             bf16* __restrict__ yb16) {
  int d = blockIdx.x * 256 + threadIdx.x;
  int t = blockIdx.y;
  int b = blockIdx.z;
  int seg = t / TS;
  size_t o = ((size_t)(b * S_ + t)) * DI_ + d;
  float y = ylocal[o];
  if (seg) {
    float cd = cumd[o];
    const float* Cp = bc + ((size_t)(b * S_ + t)) * 32 + 16;
    const float* Hb = h0seg + ((size_t)(b * NSEG + seg) * 16) * DI_ + d;
#pragma unroll
    for (int n = 0; n < 16; ++n)
      y += Cp[n] * __expf(At[(size_t)n * DI_ + d] * cd) * Hb[(size_t)n * DI_];
  }
  float z = __bfloat162float(xz[((size_t)(b * S_ + t)) * (2 * DI_) + DI_ + d]);
  float sig = 1.f / (1.f + __expf(-z));
  yb16[o] = __float2bfloat16(y * (z * sig));
}

// head stage 1: block (j,b) reduces rows s in [j*32, j*32+32)
__global__ void k_head1(const bf16* __restrict__ hf, const float* __restrict__ wh,
                        float* __restrict__ partial) {
  __shared__ float red[4];
  int b = blockIdx.y, j = blockIdx.x;
  const bf16* base = hf + ((size_t)b * S_ + j * 32) * DM_;
  float acc = 0.f;
  for (int i = threadIdx.x; i < 32 * DM_; i += 256) {
    int dd = i - (i / DM_) * DM_;
    acc += __bfloat162float(base[i]) * wh[dd];
  }
  for (int off = 32; off; off >>= 1) acc += __shfl_down(acc, off);
  if ((threadIdx.x & 63) == 0) red[threadIdx.x >> 6] = acc;
  __syncthreads();
  if (threadIdx.x == 0)
    partial[b * 16 + j] = red[0] + red[1] + red[2] + red[3];
}

__global__ void k_head2(const float* __restrict__ partial, const float* __restrict__ bh,
                        float* __restrict__ out) {
  int b = threadIdx.x;
  if (b < B_) {
    float acc = 0.f;
    for (int j = 0; j < 16; ++j) acc += partial[b * 16 + j];
    out[b] = acc * (1.f / S_) + bh[0];
  }
}

// ---------------- MFMA GEMM v6 ----------------
// 128x128 tile, BK=64, double-buffered LDS, counted vmcnt(8) depth-1 prefetch,
// chunk-major conflict-free LDS layout, XCD swizzle, split-K via blockIdx.z.
// EPI: 0 f32 out; 3 bias+softplus f32; 5 split-K partial f32; 6 bf16 out;
//      7 split-K partial bf16; 8 split-K atomicAdd into f32 dest (residual acc)
template <int EPI>
__global__ __launch_bounds__(256)
void k_gemm_mfma(const bf16* __restrict__ A, int lda,
                 const bf16* __restrict__ W, int ldw,
                 const float* __restrict__ bias,
                 void* __restrict__ out1,
                 int ldc, int N, int Kdim, int pmn) {
  __shared__ short As[2][8192];   // [buf][chunk(8)][row(128)][8]
  __shared__ short Bs[2][8192];

  int nwg = gridDim.x * gridDim.y;
  int orig = blockIdx.y * gridDim.x + blockIdx.x;
  int wg = (nwg % 8 == 0) ? ((orig & 7) * (nwg >> 3) + (orig >> 3)) : orig;
  int m0 = (wg / gridDim.x) * 128;
  int n0 = (wg % gridDim.x) * 128;

  int lane = threadIdx.x & 63;
  int wid = threadIdx.x >> 6;
  int wm = wid >> 1, wn = wid & 1;
  int lr = lane & 15;
  int ch = lane >> 4;
  int koff = blockIdx.z * Kdim;

  f32x4 acc[4][4];
#pragma unroll
  for (int i = 0; i < 4; ++i)
#pragma unroll
    for (int j = 0; j < 4; ++j) {
      acc[i][j][0] = 0.f; acc[i][j][1] = 0.f; acc[i][j][2] = 0.f; acc[i][j][3] = 0.f;
    }

#define GSTAGE(bb, kt)                                                            \
  {                                                                               \
    int k0 = koff + (kt) * 64;                                                    \
    _Pragma("unroll")                                                             \
    for (int c0 = 0; c0 < 4; ++c0) {                                              \
      int c = c0 * 256 + (int)threadIdx.x;                                        \
      int row = c & 127, chk = c >> 7;                                            \
      GLDS16(A + (size_t)(m0 + row) * lda + k0 + chk * 8,                         \
             (char*)&As[bb][0] + c * 16);                                         \
      GLDS16(W + (size_t)(n0 + row) * ldw + k0 + chk * 8,                         \
             (char*)&Bs[bb][0] + c * 16);                                         \
    }                                                                             \
  }

  int nt = Kdim / 64;
  GSTAGE(0, 0);

  for (int t = 0; t < nt; ++t) {
    int buf = t & 1;
    if (t + 1 < nt) {
      GSTAGE(buf ^ 1, t + 1);
      asm volatile("s_waitcnt vmcnt(8)" ::: "memory");
    } else {
      asm volatile("s_waitcnt vmcnt(0)" ::: "memory");
    }
    __builtin_amdgcn_s_barrier();
    __builtin_amdgcn_sched_barrier(0);

    short8 a0[4], a1[4], b0[4], b1[4];
#pragma unroll
    for (int f = 0; f < 4; ++f) {
      a0[f] = *(const short8*)&As[buf][(ch * 128 + wm * 64 + f * 16 + lr) * 8];
      b0[f] = *(const short8*)&Bs[buf][(ch * 128 + wn * 64 + f * 16 + lr) * 8];
    }
    __builtin_amdgcn_sched_barrier(0);
#pragma unroll
    for (int f = 0; f < 4; ++f) {
      a1[f] = *(const short8*)&As[buf][((4 + ch) * 128 + wm * 64 + f * 16 + lr) * 8];
      b1[f] = *(const short8*)&Bs[buf][((4 + ch) * 128 + wn * 64 + f * 16 + lr) * 8];
    }
    asm volatile("s_waitcnt lgkmcnt(8)" ::: "memory");
    __builtin_amdgcn_sched_barrier(0);
    __builtin_amdgcn_s_setprio(1);
#pragma unroll
    for (int i = 0; i < 4; ++i)
#pragma unroll
      for (int j = 0; j < 4; ++j)
        acc[i][j] = __builtin_amdgcn_mfma_f32_16x16x32_bf16(a0[i], b0[j], acc[i][j], 0, 0, 0);
    __builtin_amdgcn_sched_barrier(0);
    asm volatile("s_waitcnt lgkmcnt(0)" ::: "memory");
    __builtin_amdgcn_sched_barrier(0);
#pragma unroll
    for (int i = 0; i < 4; ++i)
#pragma unroll
      for (int j = 0; j < 4; ++j)
        acc[i][j] = __builtin_amdgcn_mfma_f32_16x16x32_bf16(a1[i], b1[j], acc[i][j], 0, 0, 0);
    __builtin_amdgcn_s_setprio(0);
    __builtin_amdgcn_sched_barrier(0);
    __builtin_amdgcn_s_barrier();
  }
#undef GSTAGE

#pragma unroll
  for (int i = 0; i < 4; ++i) {
#pragma unroll
    for (int j = 0; j < 4; ++j) {
      int nl = wn * 64 + j * 16 + (lane & 15);
      int n = n0 + nl;
#pragma unroll
      for (int q = 0; q < 4; ++q) {
        int m = m0 + wm * 64 + i * 16 + (lane >> 4) * 4 + q;
        float v = acc[i][j][q];
        if (EPI == 0) {
          ((float*)out1)[(size_t)m * ldc + n] = v;
        } else if (EPI == 3) {
          v += bias[n];
          v = (v > 20.f) ? v : log1pf(expf(v));
          ((float*)out1)[(size_t)m * ldc + n] = v;
        } else if (EPI == 5) {
          ((float*)out1)[(size_t)blockIdx.z * pmn + (size_t)m * N + n] = v;
        } else if (EPI == 6) {
          ((bf16*)out1)[(size_t)m * ldc + n] = __float2bfloat16(v);
        } else if (EPI == 7) {
          ((bf16*)out1)[(size_t)blockIdx.z * pmn + (size_t)m * N + n] = __float2bfloat16(v);
        } else if (EPI == 8) {
          atomicAdd((float*)out1 + (size_t)m * ldc + n, v);
        }
      }
    }
  }
}

// split-K reduce for xproj: sum 8 partials, emit dtp (bf16, K-padded 64) + bc (f32)
__global__ void k_xreduce(const float* __restrict__ pxp, bf16* __restrict__ dtp,
                          float* __restrict__ bcb) {
  int idx = blockIdx.x * 256 + threadIdx.x;
  if (idx >= 2048 * 128) return;
  int m = idx >> 7, n = idx & 127;
  float s = 0.f;
#pragma unroll
  for (int k = 0; k < 8; ++k) s += pxp[(size_t)k * 2048 * 128 + idx];
  if (n < 64) dtp[m * 64 + n] = __float2bfloat16(n < 48 ? s : 0.f);
  if (n >= 48 && n < 80) bcb[m * 32 + (n - 48)] = s;
}

// ---------------- launch ----------------

extern "C" void kernel_launch(void* const* d_in, const int* in_sizes, int n_in,
                              void* d_out, int out_size, void* d_ws, size_t ws_size,
                              hipStream_t stream) {
  const float* x        = (const float*)d_in[0];
  const float* w_in     = (const float*)d_in[1];
  const float* b_in     = (const float*)d_in[2];
  const float* pe       = (const float*)d_in[3];
  const float* ln1_w    = (const float*)d_in[4];
  const float* ln1_b    = (const float*)d_in[5];
  const float* w_inproj = (const float*)d_in[6];
  const float* conv_w   = (const float*)d_in[7];
  const float* conv_b   = (const float*)d_in[8];
  const float* w_xproj  = (const float*)d_in[9];
  const float* w_dt     = (const float*)d_in[10];
  const float* b_dt     = (const float*)d_in[11];
  const float* A_log    = (const float*)d_in[12];
  const float* Dv       = (const float*)d_in[13];
  const float* w_outproj= (const float*)d_in[14];
  const float* ln2_w    = (const float*)d_in[15];
  const float* ln2_b    = (const float*)d_in[16];
  const float* ff_w1    = (const float*)d_in[17];
  const float* ff_b1    = (const float*)d_in[18];
  const float* ff_w2    = (const float*)d_in[19];
  const float* ff_b2    = (const float*)d_in[20];
  const float* lnf_w    = (const float*)d_in[21];
  const float* lnf_b    = (const float*)d_in[22];
  const float* w_head   = (const float*)d_in[23];
  const float* b_head   = (const float*)d_in[24];
  float* out = (float*)d_out;

  const int M = B_ * S_;  // 2048

  float* wsf = (float*)d_ws;
  float* h    = wsf; wsf += (size_t)M * DM_;
  float* bc   = wsf; wsf += (size_t)M * 32;
  float* dlt  = wsf; wsf += (size_t)M * DI_;
  float* cumd = wsf; wsf += (size_t)M * DI_;
  float* hend = wsf; wsf += (size_t)B_ * NSEG * DI_ * 16;
  float* h0sg = wsf; wsf += (size_t)B_ * NSEG * DI_ * 16;
  float* pxp  = wsf; wsf += (size_t)4 * M * 2 * DM_;
  float* At   = wsf; wsf += (size_t)L_ * 16 * DI_;
  float* part = wsf; wsf += 64;
  bf16* wsb = (bf16*)wsf;
  bf16* xln16 = wsb; wsb += (size_t)M * DM_;
  bf16* xz16  = wsb; wsb += (size_t)M * 2 * DI_;
  bf16* xcb   = wsb; wsb += (size_t)M * DI_;
  bf16* dtp   = wsb; wsb += (size_t)M * 64;
  bf16* yb16  = wsb; wsb += (size_t)M * DI_;
  bf16* ffh16 = wsb; wsb += (size_t)M * DI_;
  bf16* wip   = wsb; wsb += (size_t)L_ * 2 * DI_ * DM_;
  bf16* wxp   = wsb; wsb += (size_t)L_ * 128 * DI_;
  bf16* wdtp  = wsb; wsb += (size_t)L_ * DI_ * 64;
  bf16* wop   = wsb; wsb += (size_t)L_ * DM_ * DI_;
  bf16* wf1   = wsb; wsb += (size_t)L_ * 2 * DM_ * DM_;
  bf16* wf2   = wsb; wsb += (size_t)L_ * DM_ * 2 * DM_;

  float* ylocal = dlt;          // scanA same-thread RAW alias (safe)
  bf16* pxp16 = (bf16*)pxp;     // bf16 split-K partials for ff1

  dim3 blk(256);

  k_castall<<<1024, blk, 0, stream>>>(w_inproj, w_outproj, ff_w1, ff_w2,
                                      w_xproj, w_dt, A_log,
                                      wip, wop, wf1, wf2, wxp, wdtp, At);

  k_embed_ln<<<M, blk, 0, stream>>>(x, w_in, b_in, pe, ln1_w, ln1_b, h, xln16);

  for (int l = 0; l < L_; ++l) {
    const float* Atl = At + (size_t)l * 16 * DI_;

    // xz = xln @ w_inproj^T -> bf16  (M x 3072, K=768)  [384 blocks, nt=12]
    k_gemm_mfma<6><<<dim3(2 * DI_ / 128, M / 128), blk, 0, stream>>>(
        xln16, DM_, wip + (size_t)l * 2 * DI_ * DM_, DM_, nullptr,
        xz16, 2 * DI_, 2 * DI_, DM_, 0);

    // conv + SiLU -> xcb only (2 d's per thread)
    k_conv_silu<<<(B_ * S_ * (DI_ / 2) + 255) / 256, blk, 0, stream>>>(
        xz16, conv_w + l * DI_ * KC_, conv_b + l * DI_, xcb);

    // xproj split-K=8 (M x 128, K'=192, nt=3) [128 blocks]
    k_gemm_mfma<5><<<dim3(1, M / 128, 8), blk, 0, stream>>>(
        xcb, DI_, wxp + (size_t)l * 128 * DI_, DI_, nullptr,
        pxp, 128, 128, DI_ / 8, M * 128);
    k_xreduce<<<(M * 128) / 256, blk, 0, stream>>>(pxp, dtp, bc);

    // delta = softplus(dtp @ wdtp^T + b_dt)   (M x 1536, K=64, nt=1) [192 blocks]
    k_gemm_mfma<3><<<dim3(DI_ / 128, M / 128), blk, 0, stream>>>(
        dtp, 64, wdtp + (size_t)l * DI_ * 64, 64, b_dt + l * DI_,
        dlt, DI_, DI_, 64, 0);

    // segmented scan (NSEG=32, TS=16)
    k_scanA<<<dim3(DI_ / 256, B_, NSEG), blk, 0, stream>>>(
        dlt, xcb, bc, Atl, Dv + l * DI_, ylocal, cumd, hend);
    k_scanB<<<(B_ * 16 * DI_ + 255) / 256, blk, 0, stream>>>(hend, cumd, Atl, h0sg);
    k_scanC<<<dim3(DI_ / 256, S_, B_), blk, 0, stream>>>(
        ylocal, cumd, bc, Atl, h0sg, xz16, yb16);

    // outproj split-K=4: atomicAdd directly into h (holds residual) [384 blocks]
    k_gemm_mfma<8><<<dim3(DM_ / 128, M / 128, 4), blk, 0, stream>>>(
        yb16, DI_, wop + (size_t)l * DM_ * DI_, DI_, nullptr,
        h, DM_, DM_, DI_ / 4, 0);
    // xln16 = LN2(h); h unchanged
    k_lnorm<<<M, blk, 0, stream>>>(h, nullptr, ln2_w + l * DM_, ln2_b + l * DM_,
                                   h, xln16);

    // ff1 split-K=2 (M x 1536, K'=384, nt=6) [384 blocks] -> bf16 partials
    k_gemm_mfma<7><<<dim3(2 * DM_ / 128, M / 128, 2), blk, 0, stream>>>(
        xln16, DM_, wf1 + (size_t)l * 2 * DM_ * DM_, DM_, nullptr,
        pxp16, 2 * DM_, 2 * DM_, DM_ / 2, M * 2 * DM_);
    k_gelred<<<(M * 2 * DM_) / 256, blk, 0, stream>>>(pxp16, ff_b1 + l * 2 * DM_, ffh16);

    // ff2 split-K=4: atomicAdd directly into h [384 blocks]
    k_gemm_mfma<8><<<dim3(DM_ / 128, M / 128, 4), blk, 0, stream>>>(
        ffh16, 2 * DM_, wf2 + (size_t)l * DM_ * 2 * DM_, 2 * DM_, nullptr,
        h, DM_, DM_, DI_ / 4, 0);
    // h += b2 (written back); xln16 = LN(h) with next-layer ln1 (or lnf)
    const float* nlw = (l + 1 < L_) ? ln1_w + (l + 1) * DM_ : lnf_w;
    const float* nlb = (l + 1 < L_) ? ln1_b + (l + 1) * DM_ : lnf_b;
    k_lnorm<<<M, blk, 0, stream>>>(h, ff_b2 + l * DM_, nlw, nlb, h, xln16);
  }

  k_head1<<<dim3(16, B_), blk, 0, stream>>>(xln16, w_head, part);
  k_head2<<<1, 64, 0, stream>>>(part, b_head, out);
}

// Round 15
// 503.220 us; speedup vs baseline: 1.0627x; 1.0627x over previous
//
#include <hip/hip_runtime.h>
#include <hip/hip_bf16.h>
#include <math.h>

#define B_ 4
#define S_ 512
#define DM_ 768
#define L_ 2
#define DI_ 1536
#define DS_ 16
#define KC_ 4
#define DTR_ 48
#define NSEG 32
#define TS 16
#define PMN_IP ((size_t)2048 * 2 * DI_)   // inproj partial chunk stride (elements)

typedef __hip_bfloat16 bf16;
typedef __attribute__((ext_vector_type(8))) short short8;
typedef __attribute__((ext_vector_type(4))) float f32x4;

#define GLDS16(g, l) __builtin_amdgcn_global_load_lds( \
    (const __attribute__((address_space(1))) void*)(g), \
    (__attribute__((address_space(3))) void*)(l), 16, 0, 0)

// ---------------- elementwise / small kernels ----------------

// fused embed + LN1: one block per row (b*S+s)
__global__ __launch_bounds__(256)
void k_embed_ln(const float* __restrict__ x, const float* __restrict__ w_in,
                const float* __restrict__ b_in, const float* __restrict__ pe,
                const float* __restrict__ lw, const float* __restrict__ lb,
                float* __restrict__ h, bf16* __restrict__ xout) {
  __shared__ float red1[4], red2[4];
  __shared__ float s_mu, s_rstd;
  int row = blockIdx.x;
  int s = row % S_;
  float xv = x[row];
  float v[3];
  float s1 = 0.f, s2 = 0.f;
#pragma unroll
  for (int j = 0; j < 3; ++j) {
    int d = threadIdx.x + j * 256;
    float t = xv * w_in[d] + b_in[d] + pe[s * DM_ + d];
    v[j] = t;
    s1 += t; s2 += t * t;
  }
  for (int off = 32; off; off >>= 1) { s1 += __shfl_down(s1, off); s2 += __shfl_down(s2, off); }
  if ((threadIdx.x & 63) == 0) { red1[threadIdx.x >> 6] = s1; red2[threadIdx.x >> 6] = s2; }
  __syncthreads();
  if (threadIdx.x == 0) {
    float t1 = red1[0] + red1[1] + red1[2] + red1[3];
    float t2 = red2[0] + red2[1] + red2[2] + red2[3];
    float mu = t1 * (1.f / DM_);
    float var = t2 * (1.f / DM_) - mu * mu;
    s_mu = mu;
    s_rstd = rsqrtf(var + 1e-5f);
  }
  __syncthreads();
  float mu = s_mu, rstd = s_rstd;
#pragma unroll
  for (int j = 0; j < 3; ++j) {
    int d = threadIdx.x + j * 256;
    h[(size_t)row * DM_ + d] = v[j];
    xout[(size_t)row * DM_ + d] = __float2bfloat16((v[j] - mu) * rstd * lw[d] + lb[d]);
  }
}

// fused split-K reduce + bias? + residual + LayerNorm: one block per row.
__global__ __launch_bounds__(256)
void k_lnred(const float* __restrict__ pxp, int KS,
             const float* __restrict__ hin, const float* __restrict__ bias,
             const float* __restrict__ lw, const float* __restrict__ lb,
             float* __restrict__ hout, bf16* __restrict__ xout) {
  __shared__ float red1[4], red2[4];
  __shared__ float s_mu, s_rstd;
  int row = blockIdx.x;
  float v[3];
  float s1 = 0.f, s2 = 0.f;
#pragma unroll
  for (int j = 0; j < 3; ++j) {
    int n = threadIdx.x + j * 256;
    float s = hin[(size_t)row * DM_ + n];
    if (bias) s += bias[n];
    for (int ks = 0; ks < KS; ++ks)
      s += pxp[(size_t)ks * 2048 * DM_ + (size_t)row * DM_ + n];
    v[j] = s;
    s1 += s; s2 += s * s;
  }
  for (int off = 32; off; off >>= 1) { s1 += __shfl_down(s1, off); s2 += __shfl_down(s2, off); }
  if ((threadIdx.x & 63) == 0) { red1[threadIdx.x >> 6] = s1; red2[threadIdx.x >> 6] = s2; }
  __syncthreads();
  if (threadIdx.x == 0) {
    float t1 = red1[0] + red1[1] + red1[2] + red1[3];
    float t2 = red2[0] + red2[1] + red2[2] + red2[3];
    float mu = t1 * (1.f / DM_);
    float var = t2 * (1.f / DM_) - mu * mu;
    s_mu = mu;
    s_rstd = rsqrtf(var + 1e-5f);
  }
  __syncthreads();
  float mu = s_mu, rstd = s_rstd;
#pragma unroll
  for (int j = 0; j < 3; ++j) {
    int n = threadIdx.x + j * 256;
    hout[(size_t)row * DM_ + n] = v[j];
    xout[(size_t)row * DM_ + n] = __float2bfloat16((v[j] - mu) * rstd * lw[n] + lb[n]);
  }
}

// fused split-K(2) reduce (bf16 partials) + bias + exact GELU -> bf16 (ff1 epilogue)
__global__ void k_gelred(const bf16* __restrict__ pxp, const float* __restrict__ bias,
                         bf16* __restrict__ out) {
  int idx = blockIdx.x * 256 + threadIdx.x;
  if (idx >= 2048 * 2 * DM_) return;
  int n = idx % (2 * DM_);
  float s = __bfloat162float(pxp[idx]) +
            __bfloat162float(pxp[(size_t)2048 * 2 * DM_ + idx]) + bias[n];
  s = 0.5f * s * (1.f + erff(s * 0.70710678118654752f));
  out[idx] = __float2bfloat16(s);
}

// ---------------- vectorized weight casts ----------------
typedef struct { unsigned short x, y, z, w; } us4;
__device__ __forceinline__ void cast4(const float* __restrict__ s, bf16* __restrict__ d) {
  float4 v = *(const float4*)s;
  us4 o;
  o.x = __bfloat16_as_ushort(__float2bfloat16(v.x));
  o.y = __bfloat16_as_ushort(__float2bfloat16(v.y));
  o.z = __bfloat16_as_ushort(__float2bfloat16(v.z));
  o.w = __bfloat16_as_ushort(__float2bfloat16(v.w));
  *(us4*)d = o;
}
__device__ __forceinline__ void store4z(bf16* __restrict__ d) {
  us4 o; o.x = o.y = o.z = o.w = 0;
  *(us4*)d = o;
}

// all weight casts (float4-vectorized) + A transpose (At = -exp(A_log), [l][n][DI])
__global__ void k_castall(const float* __restrict__ w_inproj, const float* __restrict__ w_outproj,
                          const float* __restrict__ ff_w1, const float* __restrict__ ff_w2,
                          const float* __restrict__ w_xproj, const float* __restrict__ w_dt,
                          const float* __restrict__ A_log,
                          bf16* __restrict__ wip, bf16* __restrict__ wop,
                          bf16* __restrict__ wf1, bf16* __restrict__ wf2,
                          bf16* __restrict__ wxp, bf16* __restrict__ wdtp,
                          float* __restrict__ At) {
  const int N0 = L_ * 2 * DI_ * DM_;
  const int N1 = L_ * DM_ * DI_;
  const int N2 = L_ * 2 * DM_ * DM_;
  const int N3 = L_ * DM_ * 2 * DM_;
  const int N4 = L_ * 128 * DI_;
  const int N5 = L_ * DI_ * 64;
  const int N6 = L_ * 16 * DI_;
  const int T4 = (N0 + N1 + N2 + N3 + N4 + N5) >> 2;
  int tid = blockIdx.x * 256 + threadIdx.x;
  int stride = gridDim.x * 256;
  for (int v = tid; v < T4; v += stride) {
    int j = v << 2;
    if (j < N0) { cast4(w_inproj + j, wip + j); continue; }
    j -= N0;
    if (j < N1) { cast4(w_outproj + j, wop + j); continue; }
    j -= N1;
    if (j < N2) { cast4(ff_w1 + j, wf1 + j); continue; }
    j -= N2;
    if (j < N3) { cast4(ff_w2 + j, wf2 + j); continue; }
    j -= N3;
    if (j < N4) {
      int col = j % DI_;
      int row = (j / DI_) & 127;
      int l = j / (128 * DI_);
      if (row < 80) cast4(&w_xproj[((size_t)l * 80 + row) * DI_ + col], wxp + j);
      else store4z(wxp + j);
      continue;
    }
    j -= N4;
    {
      int col = j & 63;
      int r = (j >> 6) % DI_;
      int l = j / (DI_ * 64);
      if (col < 48) cast4(&w_dt[((size_t)l * DI_ + r) * 48 + col], wdtp + j);
      else store4z(wdtp + j);
    }
  }
  for (int j = tid; j < N6; j += stride) {
    int d = j % DI_;
    int n = (j / DI_) & 15;
    int l = j / (16 * DI_);
    At[j] = -__expf(A_log[((size_t)l * DI_ + d) * 16 + n]);
  }
}

// depthwise causal conv (K=4) + bias + SiLU over SUM of 2 bf16 inproj partials;
// 2 d's per thread, ushort2 loads/stores
__global__ void k_conv_silu(const bf16* __restrict__ pip, const float* __restrict__ cw,
                            const float* __restrict__ cb, bf16* __restrict__ xcb) {
  int idx = blockIdx.x * 256 + threadIdx.x;
  if (idx >= B_ * S_ * (DI_ / 2)) return;
  int d2 = idx % (DI_ / 2);
  int d = d2 * 2;
  int t = idx / (DI_ / 2);
  int s = t % S_;
  int b = t / S_;
  float a0 = cb[d], a1 = cb[d + 1];
  const bf16* p0 = pip + (size_t)(b * S_) * (2 * DI_) + d;
  const bf16* p1 = p0 + PMN_IP;
#pragma unroll
  for (int k = 0; k < KC_; ++k) {
    int ss = s - (KC_ - 1) + k;
    if (ss >= 0) {
      ushort2 u0 = *(const ushort2*)&p0[(size_t)ss * (2 * DI_)];
      ushort2 u1 = *(const ushort2*)&p1[(size_t)ss * (2 * DI_)];
      float x0 = __bfloat162float(__ushort_as_bfloat16(u0.x)) +
                 __bfloat162float(__ushort_as_bfloat16(u1.x));
      float x1 = __bfloat162float(__ushort_as_bfloat16(u0.y)) +
                 __bfloat162float(__ushort_as_bfloat16(u1.y));
      a0 = fmaf(x0, cw[d * KC_ + k], a0);
      a1 = fmaf(x1, cw[(d + 1) * KC_ + k], a1);
    }
  }
  float v0 = a0 / (1.f + expf(-a0));
  float v1 = a1 / (1.f + expf(-a1));
  ushort2 o;
  o.x = __bfloat16_as_ushort(__float2bfloat16(v0));
  o.y = __bfloat16_as_ushort(__float2bfloat16(v1));
  *(ushort2*)&xcb[(size_t)t * DI_ + d] = o;
}

// ---------------- segmented selective scan ----------------
// Pass A: one thread per d; u read from xcb (bf16); 16 states in VGPRs.
__global__ __launch_bounds__(256)
void k_scanA(const float* __restrict__ delta, const bf16* __restrict__ xcb,
             const float* __restrict__ bc, const float* __restrict__ At,
             const float* __restrict__ Dv,
             float* __restrict__ ylocal, float* __restrict__ cumd,
             float* __restrict__ hend) {
  int b = blockIdx.y;
  int seg = blockIdx.z;
  int d = blockIdx.x * 256 + threadIdx.x;
  int s0 = seg * TS;

  float A[16], hst[16];
#pragma unroll
  for (int n = 0; n < 16; ++n) {
    A[n] = At[(size_t)n * DI_ + d];
    hst[n] = 0.f;
  }
  float Dd = Dv[d];
  float cd = 0.f;

  const float* dp = delta + ((size_t)(b * S_ + s0)) * DI_ + d;
  const bf16* up = xcb + ((size_t)(b * S_ + s0)) * DI_ + d;
  const float* bp = bc + ((size_t)(b * S_ + s0)) * 32;
  float* yp = ylocal + ((size_t)(b * S_ + s0)) * DI_ + d;
  float* cp = cumd + ((size_t)(b * S_ + s0)) * DI_ + d;

  float dl_next = dp[0];
  float u_next = __bfloat162float(up[0]);
#pragma unroll 4
  for (int s = 0; s < TS; ++s) {
    float dl = dl_next, u = u_next;
    if (s + 1 < TS) {
      dl_next = dp[(size_t)(s + 1) * DI_];
      u_next = __bfloat162float(up[(size_t)(s + 1) * DI_]);
    }
    cd += dl;
    float dlu = dl * u;
    float y = 0.f;
#pragma unroll
    for (int n = 0; n < 16; ++n) {
      float e = __expf(dl * A[n]);
      hst[n] = fmaf(hst[n], e, dlu * bp[s * 32 + n]);
      y = fmaf(hst[n], bp[s * 32 + 16 + n], y);
    }
    yp[(size_t)s * DI_] = fmaf(u, Dd, y);
    cp[(size_t)s * DI_] = cd;
  }
  float* hp = hend + ((size_t)(b * NSEG + seg) * 16) * DI_ + d;
#pragma unroll
  for (int n = 0; n < 16; ++n) hp[(size_t)n * DI_] = hst[n];
}

__global__ void k_scanB(const float* __restrict__ hend, const float* __restrict__ cumd,
                        const float* __restrict__ At, float* __restrict__ h0seg) {
  int idx = blockIdx.x * 256 + threadIdx.x;
  if (idx >= B_ * 16 * DI_) return;
  int d = idx % DI_;
  int r = idx / DI_;
  int n = r & 15;
  int b = r >> 4;
  float A = At[(size_t)n * DI_ + d];
  float h0 = 0.f;
  for (int seg = 0; seg < NSEG; ++seg) {
    size_t o = ((size_t)(b * NSEG + seg) * 16 + n) * DI_ + d;
    h0seg[o] = h0;
    float cdt = cumd[((size_t)(b * S_ + seg * TS + TS - 1)) * DI_ + d];
    h0 = h0 * __expf(A * cdt) + hend[o];
  }
}

// Pass C: z comes from the SUM of the 2 bf16 inproj partials (z half)
__global__ __launch_bounds__(256)
void k_scanC(const float* __restrict__ ylocal, const float* __restrict__ cumd,
             const float* __restrict__ bc, const float* __restrict__ At,
             const float* __restrict__ h0seg, const bf16* __restrict__ pip,
             bf16* __restrict__ yb16) {
  int d = blockIdx.x * 256 + threadIdx.x;
  int t = blockIdx.y;
  int b = blockIdx.z;
  int seg = t / TS;
  size_t o = ((size_t)(b * S_ + t)) * DI_ + d;
  float y = ylocal[o];
  if (seg) {
    float cd = cumd[o];
    const float* Cp = bc + ((size_t)(b * S_ + t)) * 32 + 16;
    const float* Hb = h0seg + ((size_t)(b * NSEG + seg) * 16) * DI_ + d;
#pragma unroll
    for (int n = 0; n < 16; ++n)
      y += Cp[n] * __expf(At[(size_t)n * DI_ + d] * cd) * Hb[(size_t)n * DI_];
  }
  size_t oz = ((size_t)(b * S_ + t)) * (2 * DI_) + DI_ + d;
  float z = __bfloat162float(pip[oz]) + __bfloat162float(pip[PMN_IP + oz]);
  float sig = 1.f / (1.f + __expf(-z));
  yb16[o] = __float2bfloat16(y * (z * sig));
}

// head stage 1: block (j,b) reduces rows s in [j*32, j*32+32)
__global__ void k_head1(const bf16* __restrict__ hf, const float* __restrict__ wh,
                        float* __restrict__ partial) {
  __shared__ float red[4];
  int b = blockIdx.y, j = blockIdx.x;
  const bf16* base = hf + ((size_t)b * S_ + j * 32) * DM_;
  float acc = 0.f;
  for (int i = threadIdx.x; i < 32 * DM_; i += 256) {
    int dd = i - (i / DM_) * DM_;
    acc += __bfloat162float(base[i]) * wh[dd];
  }
  for (int off = 32; off; off >>= 1) acc += __shfl_down(acc, off);
  if ((threadIdx.x & 63) == 0) red[threadIdx.x >> 6] = acc;
  __syncthreads();
  if (threadIdx.x == 0)
    partial[b * 16 + j] = red[0] + red[1] + red[2] + red[3];
}

__global__ void k_head2(const float* __restrict__ partial, const float* __restrict__ bh,
                        float* __restrict__ out) {
  int b = threadIdx.x;
  if (b < B_) {
    float acc = 0.f;
    for (int j = 0; j < 16; ++j) acc += partial[b * 16 + j];
    out[b] = acc * (1.f / S_) + bh[0];
  }
}

// ---------------- MFMA GEMM v5 ----------------
// 128x128 tile, BK=64, double-buffered LDS, counted vmcnt(8) depth-1 prefetch,
// chunk-major conflict-free LDS layout, XCD swizzle, split-K via blockIdx.z.
// EPI: 0 f32 out; 3 bias+softplus f32; 5 split-K partial f32; 6 bf16 out;
//      7 split-K partial bf16
template <int EPI>
__global__ __launch_bounds__(256)
void k_gemm_mfma(const bf16* __restrict__ A, int lda,
                 const bf16* __restrict__ W, int ldw,
                 const float* __restrict__ bias,
                 void* __restrict__ out1,
                 int ldc, int N, int Kdim, int pmn) {
  __shared__ short As[2][8192];   // [buf][chunk(8)][row(128)][8]
  __shared__ short Bs[2][8192];

  int nwg = gridDim.x * gridDim.y;
  int orig = blockIdx.y * gridDim.x + blockIdx.x;
  int wg = (nwg % 8 == 0) ? ((orig & 7) * (nwg >> 3) + (orig >> 3)) : orig;
  int m0 = (wg / gridDim.x) * 128;
  int n0 = (wg % gridDim.x) * 128;

  int lane = threadIdx.x & 63;
  int wid = threadIdx.x >> 6;
  int wm = wid >> 1, wn = wid & 1;
  int lr = lane & 15;
  int ch = lane >> 4;
  int koff = blockIdx.z * Kdim;

  f32x4 acc[4][4];
#pragma unroll
  for (int i = 0; i < 4; ++i)
#pragma unroll
    for (int j = 0; j < 4; ++j) {
      acc[i][j][0] = 0.f; acc[i][j][1] = 0.f; acc[i][j][2] = 0.f; acc[i][j][3] = 0.f;
    }

#define GSTAGE(bb, kt)                                                            \
  {                                                                               \
    int k0 = koff + (kt) * 64;                                                    \
    _Pragma("unroll")                                                             \
    for (int c0 = 0; c0 < 4; ++c0) {                                              \
      int c = c0 * 256 + (int)threadIdx.x;                                        \
      int row = c & 127, chk = c >> 7;                                            \
      GLDS16(A + (size_t)(m0 + row) * lda + k0 + chk * 8,                         \
             (char*)&As[bb][0] + c * 16);                                         \
      GLDS16(W + (size_t)(n0 + row) * ldw + k0 + chk * 8,                         \
             (char*)&Bs[bb][0] + c * 16);                                         \
    }                                                                             \
  }

  int nt = Kdim / 64;
  GSTAGE(0, 0);

  for (int t = 0; t < nt; ++t) {
    int buf = t & 1;
    if (t + 1 < nt) {
      GSTAGE(buf ^ 1, t + 1);
      asm volatile("s_waitcnt vmcnt(8)" ::: "memory");
    } else {
      asm volatile("s_waitcnt vmcnt(0)" ::: "memory");
    }
    __builtin_amdgcn_s_barrier();
    __builtin_amdgcn_sched_barrier(0);

    short8 a0[4], a1[4], b0[4], b1[4];
#pragma unroll
    for (int f = 0; f < 4; ++f) {
      a0[f] = *(const short8*)&As[buf][(ch * 128 + wm * 64 + f * 16 + lr) * 8];
      b0[f] = *(const short8*)&Bs[buf][(ch * 128 + wn * 64 + f * 16 + lr) * 8];
    }
    __builtin_amdgcn_sched_barrier(0);
#pragma unroll
    for (int f = 0; f < 4; ++f) {
      a1[f] = *(const short8*)&As[buf][((4 + ch) * 128 + wm * 64 + f * 16 + lr) * 8];
      b1[f] = *(const short8*)&Bs[buf][((4 + ch) * 128 + wn * 64 + f * 16 + lr) * 8];
    }
    asm volatile("s_waitcnt lgkmcnt(8)" ::: "memory");
    __builtin_amdgcn_sched_barrier(0);
    __builtin_amdgcn_s_setprio(1);
#pragma unroll
    for (int i = 0; i < 4; ++i)
#pragma unroll
      for (int j = 0; j < 4; ++j)
        acc[i][j] = __builtin_amdgcn_mfma_f32_16x16x32_bf16(a0[i], b0[j], acc[i][j], 0, 0, 0);
    __builtin_amdgcn_sched_barrier(0);
    asm volatile("s_waitcnt lgkmcnt(0)" ::: "memory");
    __builtin_amdgcn_sched_barrier(0);
#pragma unroll
    for (int i = 0; i < 4; ++i)
#pragma unroll
      for (int j = 0; j < 4; ++j)
        acc[i][j] = __builtin_amdgcn_mfma_f32_16x16x32_bf16(a1[i], b1[j], acc[i][j], 0, 0, 0);
    __builtin_amdgcn_s_setprio(0);
    __builtin_amdgcn_sched_barrier(0);
    __builtin_amdgcn_s_barrier();
  }
#undef GSTAGE

#pragma unroll
  for (int i = 0; i < 4; ++i) {
#pragma unroll
    for (int j = 0; j < 4; ++j) {
      int nl = wn * 64 + j * 16 + (lane & 15);
      int n = n0 + nl;
#pragma unroll
      for (int q = 0; q < 4; ++q) {
        int m = m0 + wm * 64 + i * 16 + (lane >> 4) * 4 + q;
        float v = acc[i][j][q];
        if (EPI == 0) {
          ((float*)out1)[(size_t)m * ldc + n] = v;
        } else if (EPI == 3) {
          v += bias[n];
          v = (v > 20.f) ? v : log1pf(expf(v));
          ((float*)out1)[(size_t)m * ldc + n] = v;
        } else if (EPI == 5) {
          ((float*)out1)[(size_t)blockIdx.z * pmn + (size_t)m * N + n] = v;
        } else if (EPI == 6) {
          ((bf16*)out1)[(size_t)m * ldc + n] = __float2bfloat16(v);
        } else if (EPI == 7) {
          ((bf16*)out1)[(size_t)blockIdx.z * pmn + (size_t)m * N + n] = __float2bfloat16(v);
        }
      }
    }
  }
}

// split-K reduce for xproj: sum 8 partials, emit dtp (bf16, K-padded 64) + bc (f32)
__global__ void k_xreduce(const float* __restrict__ pxp, bf16* __restrict__ dtp,
                          float* __restrict__ bcb) {
  int idx = blockIdx.x * 256 + threadIdx.x;
  if (idx >= 2048 * 128) return;
  int m = idx >> 7, n = idx & 127;
  float s = 0.f;
#pragma unroll
  for (int k = 0; k < 8; ++k) s += pxp[(size_t)k * 2048 * 128 + idx];
  if (n < 64) dtp[m * 64 + n] = __float2bfloat16(n < 48 ? s : 0.f);
  if (n >= 48 && n < 80) bcb[m * 32 + (n - 48)] = s;
}

// ---------------- launch ----------------

extern "C" void kernel_launch(void* const* d_in, const int* in_sizes, int n_in,
                              void* d_out, int out_size, void* d_ws, size_t ws_size,
                              hipStream_t stream) {
  const float* x        = (const float*)d_in[0];
  const float* w_in     = (const float*)d_in[1];
  const float* b_in     = (const float*)d_in[2];
  const float* pe       = (const float*)d_in[3];
  const float* ln1_w    = (const float*)d_in[4];
  const float* ln1_b    = (const float*)d_in[5];
  const float* w_inproj = (const float*)d_in[6];
  const float* conv_w   = (const float*)d_in[7];
  const float* conv_b   = (const float*)d_in[8];
  const float* w_xproj  = (const float*)d_in[9];
  const float* w_dt     = (const float*)d_in[10];
  const float* b_dt     = (const float*)d_in[11];
  const float* A_log    = (const float*)d_in[12];
  const float* Dv       = (const float*)d_in[13];
  const float* w_outproj= (const float*)d_in[14];
  const float* ln2_w    = (const float*)d_in[15];
  const float* ln2_b    = (const float*)d_in[16];
  const float* ff_w1    = (const float*)d_in[17];
  const float* ff_b1    = (const float*)d_in[18];
  const float* ff_w2    = (const float*)d_in[19];
  const float* ff_b2    = (const float*)d_in[20];
  const float* lnf_w    = (const float*)d_in[21];
  const float* lnf_b    = (const float*)d_in[22];
  const float* w_head   = (const float*)d_in[23];
  const float* b_head   = (const float*)d_in[24];
  float* out = (float*)d_out;

  const int M = B_ * S_;  // 2048

  float* wsf = (float*)d_ws;
  float* h    = wsf; wsf += (size_t)M * DM_;
  float* bc   = wsf; wsf += (size_t)M * 32;
  float* dlt  = wsf; wsf += (size_t)M * DI_;
  float* cumd = wsf; wsf += (size_t)M * DI_;
  float* hend = wsf; wsf += (size_t)B_ * NSEG * DI_ * 16;
  float* h0sg = wsf; wsf += (size_t)B_ * NSEG * DI_ * 16;
  float* pxp  = wsf; wsf += (size_t)4 * M * 2 * DM_;
  float* At   = wsf; wsf += (size_t)L_ * 16 * DI_;
  float* part = wsf; wsf += 64;
  bf16* wsb = (bf16*)wsf;
  bf16* xln16 = wsb; wsb += (size_t)M * DM_;
  bf16* pip   = wsb; wsb += 2 * PMN_IP;            // inproj bf16 partials (2 chunks)
  bf16* xcb   = wsb; wsb += (size_t)M * DI_;
  bf16* dtp   = wsb; wsb += (size_t)M * 64;
  bf16* yb16  = wsb; wsb += (size_t)M * DI_;
  bf16* ffh16 = wsb; wsb += (size_t)M * DI_;
  bf16* wip   = wsb; wsb += (size_t)L_ * 2 * DI_ * DM_;
  bf16* wxp   = wsb; wsb += (size_t)L_ * 128 * DI_;
  bf16* wdtp  = wsb; wsb += (size_t)L_ * DI_ * 64;
  bf16* wop   = wsb; wsb += (size_t)L_ * DM_ * DI_;
  bf16* wf1   = wsb; wsb += (size_t)L_ * 2 * DM_ * DM_;
  bf16* wf2   = wsb; wsb += (size_t)L_ * DM_ * 2 * DM_;

  float* ylocal = dlt;          // scanA same-thread RAW alias (safe)
  bf16* pxp16 = (bf16*)pxp;     // bf16 split-K partials for ff1

  dim3 blk(256);

  k_castall<<<1024, blk, 0, stream>>>(w_inproj, w_outproj, ff_w1, ff_w2,
                                      w_xproj, w_dt, A_log,
                                      wip, wop, wf1, wf2, wxp, wdtp, At);

  k_embed_ln<<<M, blk, 0, stream>>>(x, w_in, b_in, pe, ln1_w, ln1_b, h, xln16);

  for (int l = 0; l < L_; ++l) {
    const float* Atl = At + (size_t)l * 16 * DI_;

    // inproj split-K=2 -> bf16 partials pip  (M x 3072, K'=384, nt=6) [768 blocks]
    k_gemm_mfma<7><<<dim3(2 * DI_ / 128, M / 128, 2), blk, 0, stream>>>(
        xln16, DM_, wip + (size_t)l * 2 * DI_ * DM_, DM_, nullptr,
        pip, 2 * DI_, 2 * DI_, DM_ / 2, (int)PMN_IP);

    // conv + SiLU over summed partials -> xcb
    k_conv_silu<<<(B_ * S_ * (DI_ / 2) + 255) / 256, blk, 0, stream>>>(
        pip, conv_w + l * DI_ * KC_, conv_b + l * DI_, xcb);

    // xproj split-K=8 (M x 128, K'=192, nt=3) [128 blocks]
    k_gemm_mfma<5><<<dim3(1, M / 128, 8), blk, 0, stream>>>(
        xcb, DI_, wxp + (size_t)l * 128 * DI_, DI_, nullptr,
        pxp, 128, 128, DI_ / 8, M * 128);
    k_xreduce<<<(M * 128) / 256, blk, 0, stream>>>(pxp, dtp, bc);

    // delta = softplus(dtp @ wdtp^T + b_dt)   (M x 1536, K=64, nt=1) [192 blocks]
    k_gemm_mfma<3><<<dim3(DI_ / 128, M / 128), blk, 0, stream>>>(
        dtp, 64, wdtp + (size_t)l * DI_ * 64, 64, b_dt + l * DI_,
        dlt, DI_, DI_, 64, 0);

    // segmented scan (NSEG=32, TS=16)
    k_scanA<<<dim3(DI_ / 256, B_, NSEG), blk, 0, stream>>>(
        dlt, xcb, bc, Atl, Dv + l * DI_, ylocal, cumd, hend);
    k_scanB<<<(B_ * 16 * DI_ + 255) / 256, blk, 0, stream>>>(hend, cumd, Atl, h0sg);
    k_scanC<<<dim3(DI_ / 256, S_, B_), blk, 0, stream>>>(
        ylocal, cumd, bc, Atl, h0sg, pip, yb16);

    // outproj split-K=4 (M x 768, K'=384, nt=6) [384 blocks] -> f32 partials
    k_gemm_mfma<5><<<dim3(DM_ / 128, M / 128, 4), blk, 0, stream>>>(
        yb16, DI_, wop + (size_t)l * DM_ * DI_, DI_, nullptr,
        pxp, DM_, DM_, DI_ / 4, M * DM_);
    k_lnred<<<M, blk, 0, stream>>>(pxp, 4, h, nullptr,
                                   ln2_w + l * DM_, ln2_b + l * DM_, h, xln16);

    // ff1 split-K=2 (M x 1536, K'=384, nt=6) [384 blocks] -> bf16 partials
    k_gemm_mfma<7><<<dim3(2 * DM_ / 128, M / 128, 2), blk, 0, stream>>>(
        xln16, DM_, wf1 + (size_t)l * 2 * DM_ * DM_, DM_, nullptr,
        pxp16, 2 * DM_, 2 * DM_, DM_ / 2, M * 2 * DM_);
    k_gelred<<<(M * 2 * DM_) / 256, blk, 0, stream>>>(pxp16, ff_b1 + l * 2 * DM_, ffh16);

    // ff2 split-K=4 (M x 768, K'=384, nt=6) [384 blocks] -> f32 partials
    k_gemm_mfma<5><<<dim3(DM_ / 128, M / 128, 4), blk, 0, stream>>>(
        ffh16, 2 * DM_, wf2 + (size_t)l * DM_ * 2 * DM_, 2 * DM_, nullptr,
        pxp, DM_, DM_, DI_ / 4, M * DM_);
    const float* nlw = (l + 1 < L_) ? ln1_w + (l + 1) * DM_ : lnf_w;
    const float* nlb = (l + 1 < L_) ? ln1_b + (l + 1) * DM_ : lnf_b;
    k_lnred<<<M, blk, 0, stream>>>(pxp, 4, h, ff_b2 + l * DM_, nlw, nlb, h, xln16);
  }

  k_head1<<<dim3(16, B_), blk, 0, stream>>>(xln16, w_head, part);
  k_head2<<<1, 64, 0, stream>>>(part, b_head, out);
}

// Round 16
// 497.728 us; speedup vs baseline: 1.0744x; 1.0110x over previous
//
#include <hip/hip_runtime.h>
#include <hip/hip_bf16.h>
#include <math.h>

#define B_ 4
#define S_ 512
#define DM_ 768
#define L_ 2
#define DI_ 1536
#define DS_ 16
#define KC_ 4
#define DTR_ 48
#define NSEG 32
#define TS 16
#define PMN_IP ((size_t)2048 * 2 * DI_)   // inproj partial chunk stride (elements)

typedef __hip_bfloat16 bf16;
typedef __attribute__((ext_vector_type(8))) short short8;
typedef __attribute__((ext_vector_type(4))) float f32x4;

#define GLDS16(g, l) __builtin_amdgcn_global_load_lds( \
    (const __attribute__((address_space(1))) void*)(g), \
    (__attribute__((address_space(3))) void*)(l), 16, 0, 0)

// ---------------- vectorized cast helpers ----------------
typedef struct { unsigned short x, y, z, w; } us4;
__device__ __forceinline__ void cast4(const float* __restrict__ s, bf16* __restrict__ d) {
  float4 v = *(const float4*)s;
  us4 o;
  o.x = __bfloat16_as_ushort(__float2bfloat16(v.x));
  o.y = __bfloat16_as_ushort(__float2bfloat16(v.y));
  o.z = __bfloat16_as_ushort(__float2bfloat16(v.z));
  o.w = __bfloat16_as_ushort(__float2bfloat16(v.w));
  *(us4*)d = o;
}
__device__ __forceinline__ void store4z(bf16* __restrict__ d) {
  us4 o; o.x = o.y = o.z = o.w = 0;
  *(us4*)d = o;
}

// ---------------- merged init: embed+LN1 (blocks 0..2047) + weight casts ----------------
__global__ __launch_bounds__(256)
void k_init(const float* __restrict__ x, const float* __restrict__ w_in,
            const float* __restrict__ b_in, const float* __restrict__ pe,
            const float* __restrict__ lw, const float* __restrict__ lb,
            float* __restrict__ h, bf16* __restrict__ xout,
            const float* __restrict__ w_inproj, const float* __restrict__ w_outproj,
            const float* __restrict__ ff_w1, const float* __restrict__ ff_w2,
            const float* __restrict__ w_xproj, const float* __restrict__ w_dt,
            const float* __restrict__ A_log,
            bf16* __restrict__ wip, bf16* __restrict__ wop,
            bf16* __restrict__ wf1, bf16* __restrict__ wf2,
            bf16* __restrict__ wxp, bf16* __restrict__ wdtp,
            float* __restrict__ At) {
  if (blockIdx.x < 2048) {
    // ---- embed + LN1, one block per row ----
    __shared__ float red1[4], red2[4];
    __shared__ float s_mu, s_rstd;
    int row = blockIdx.x;
    int s = row % S_;
    float xv = x[row];
    float v[3];
    float s1 = 0.f, s2 = 0.f;
#pragma unroll
    for (int j = 0; j < 3; ++j) {
      int d = threadIdx.x + j * 256;
      float t = xv * w_in[d] + b_in[d] + pe[s * DM_ + d];
      v[j] = t;
      s1 += t; s2 += t * t;
    }
    for (int off = 32; off; off >>= 1) { s1 += __shfl_down(s1, off); s2 += __shfl_down(s2, off); }
    if ((threadIdx.x & 63) == 0) { red1[threadIdx.x >> 6] = s1; red2[threadIdx.x >> 6] = s2; }
    __syncthreads();
    if (threadIdx.x == 0) {
      float t1 = red1[0] + red1[1] + red1[2] + red1[3];
      float t2 = red2[0] + red2[1] + red2[2] + red2[3];
      float mu = t1 * (1.f / DM_);
      float var = t2 * (1.f / DM_) - mu * mu;
      s_mu = mu;
      s_rstd = rsqrtf(var + 1e-5f);
    }
    __syncthreads();
    float mu = s_mu, rstd = s_rstd;
#pragma unroll
    for (int j = 0; j < 3; ++j) {
      int d = threadIdx.x + j * 256;
      h[(size_t)row * DM_ + d] = v[j];
      xout[(size_t)row * DM_ + d] = __float2bfloat16((v[j] - mu) * rstd * lw[d] + lb[d]);
    }
    return;
  }
  // ---- weight casts (grid-strided over 1024 blocks) ----
  const int N0 = L_ * 2 * DI_ * DM_;
  const int N1 = L_ * DM_ * DI_;
  const int N2 = L_ * 2 * DM_ * DM_;
  const int N3 = L_ * DM_ * 2 * DM_;
  const int N4 = L_ * 128 * DI_;
  const int N5 = L_ * DI_ * 64;
  const int N6 = L_ * 16 * DI_;
  const int T4 = (N0 + N1 + N2 + N3 + N4 + N5) >> 2;
  int tid = (blockIdx.x - 2048) * 256 + threadIdx.x;
  int stride = 1024 * 256;
  for (int v = tid; v < T4; v += stride) {
    int j = v << 2;
    if (j < N0) { cast4(w_inproj + j, wip + j); continue; }
    j -= N0;
    if (j < N1) { cast4(w_outproj + j, wop + j); continue; }
    j -= N1;
    if (j < N2) { cast4(ff_w1 + j, wf1 + j); continue; }
    j -= N2;
    if (j < N3) { cast4(ff_w2 + j, wf2 + j); continue; }
    j -= N3;
    if (j < N4) {
      int col = j % DI_;
      int row = (j / DI_) & 127;
      int l = j / (128 * DI_);
      if (row < 80) cast4(&w_xproj[((size_t)l * 80 + row) * DI_ + col], wxp + j);
      else store4z(wxp + j);
      continue;
    }
    j -= N4;
    {
      int col = j & 63;
      int r = (j >> 6) % DI_;
      int l = j / (DI_ * 64);
      if (col < 48) cast4(&w_dt[((size_t)l * DI_ + r) * 48 + col], wdtp + j);
      else store4z(wdtp + j);
    }
  }
  for (int j = tid; j < N6; j += stride) {
    int d = j % DI_;
    int n = (j / DI_) & 15;
    int l = j / (16 * DI_);
    At[j] = -__expf(A_log[((size_t)l * DI_ + d) * 16 + n]);
  }
}

// fused split-K reduce (bf16 partials) + bias? + residual + LayerNorm: one block/row
__global__ __launch_bounds__(256)
void k_lnred(const bf16* __restrict__ pxp, int KS,
             const float* __restrict__ hin, const float* __restrict__ bias,
             const float* __restrict__ lw, const float* __restrict__ lb,
             float* __restrict__ hout, bf16* __restrict__ xout) {
  __shared__ float red1[4], red2[4];
  __shared__ float s_mu, s_rstd;
  int row = blockIdx.x;
  float v[3];
  float s1 = 0.f, s2 = 0.f;
#pragma unroll
  for (int j = 0; j < 3; ++j) {
    int n = threadIdx.x + j * 256;
    float s = hin[(size_t)row * DM_ + n];
    if (bias) s += bias[n];
    for (int ks = 0; ks < KS; ++ks)
      s += __bfloat162float(pxp[(size_t)ks * 2048 * DM_ + (size_t)row * DM_ + n]);
    v[j] = s;
    s1 += s; s2 += s * s;
  }
  for (int off = 32; off; off >>= 1) { s1 += __shfl_down(s1, off); s2 += __shfl_down(s2, off); }
  if ((threadIdx.x & 63) == 0) { red1[threadIdx.x >> 6] = s1; red2[threadIdx.x >> 6] = s2; }
  __syncthreads();
  if (threadIdx.x == 0) {
    float t1 = red1[0] + red1[1] + red1[2] + red1[3];
    float t2 = red2[0] + red2[1] + red2[2] + red2[3];
    float mu = t1 * (1.f / DM_);
    float var = t2 * (1.f / DM_) - mu * mu;
    s_mu = mu;
    s_rstd = rsqrtf(var + 1e-5f);
  }
  __syncthreads();
  float mu = s_mu, rstd = s_rstd;
#pragma unroll
  for (int j = 0; j < 3; ++j) {
    int n = threadIdx.x + j * 256;
    hout[(size_t)row * DM_ + n] = v[j];
    xout[(size_t)row * DM_ + n] = __float2bfloat16((v[j] - mu) * rstd * lw[n] + lb[n]);
  }
}

// fused split-K(2) reduce (bf16 partials) + bias + exact GELU -> bf16 (ff1 epilogue)
__global__ void k_gelred(const bf16* __restrict__ pxp, const float* __restrict__ bias,
                         bf16* __restrict__ out) {
  int idx = blockIdx.x * 256 + threadIdx.x;
  if (idx >= 2048 * 2 * DM_) return;
  int n = idx % (2 * DM_);
  float s = __bfloat162float(pxp[idx]) +
            __bfloat162float(pxp[(size_t)2048 * 2 * DM_ + idx]) + bias[n];
  s = 0.5f * s * (1.f + erff(s * 0.70710678118654752f));
  out[idx] = __float2bfloat16(s);
}

// depthwise causal conv (K=4) + bias + SiLU over SUM of 2 bf16 inproj partials;
// 2 d's per thread, ushort2 loads/stores
__global__ void k_conv_silu(const bf16* __restrict__ pip, const float* __restrict__ cw,
                            const float* __restrict__ cb, bf16* __restrict__ xcb) {
  int idx = blockIdx.x * 256 + threadIdx.x;
  if (idx >= B_ * S_ * (DI_ / 2)) return;
  int d2 = idx % (DI_ / 2);
  int d = d2 * 2;
  int t = idx / (DI_ / 2);
  int s = t % S_;
  int b = t / S_;
  float a0 = cb[d], a1 = cb[d + 1];
  const bf16* p0 = pip + (size_t)(b * S_) * (2 * DI_) + d;
  const bf16* p1 = p0 + PMN_IP;
#pragma unroll
  for (int k = 0; k < KC_; ++k) {
    int ss = s - (KC_ - 1) + k;
    if (ss >= 0) {
      ushort2 u0 = *(const ushort2*)&p0[(size_t)ss * (2 * DI_)];
      ushort2 u1 = *(const ushort2*)&p1[(size_t)ss * (2 * DI_)];
      float x0 = __bfloat162float(__ushort_as_bfloat16(u0.x)) +
                 __bfloat162float(__ushort_as_bfloat16(u1.x));
      float x1 = __bfloat162float(__ushort_as_bfloat16(u0.y)) +
                 __bfloat162float(__ushort_as_bfloat16(u1.y));
      a0 = fmaf(x0, cw[d * KC_ + k], a0);
      a1 = fmaf(x1, cw[(d + 1) * KC_ + k], a1);
    }
  }
  float v0 = a0 / (1.f + expf(-a0));
  float v1 = a1 / (1.f + expf(-a1));
  ushort2 o;
  o.x = __bfloat16_as_ushort(__float2bfloat16(v0));
  o.y = __bfloat16_as_ushort(__float2bfloat16(v1));
  *(ushort2*)&xcb[(size_t)t * DI_ + d] = o;
}

// ---------------- segmented selective scan ----------------
__global__ __launch_bounds__(256)
void k_scanA(const float* __restrict__ delta, const bf16* __restrict__ xcb,
             const float* __restrict__ bc, const float* __restrict__ At,
             const float* __restrict__ Dv,
             float* __restrict__ ylocal, float* __restrict__ cumd,
             float* __restrict__ hend) {
  int b = blockIdx.y;
  int seg = blockIdx.z;
  int d = blockIdx.x * 256 + threadIdx.x;
  int s0 = seg * TS;

  float A[16], hst[16];
#pragma unroll
  for (int n = 0; n < 16; ++n) {
    A[n] = At[(size_t)n * DI_ + d];
    hst[n] = 0.f;
  }
  float Dd = Dv[d];
  float cd = 0.f;

  const float* dp = delta + ((size_t)(b * S_ + s0)) * DI_ + d;
  const bf16* up = xcb + ((size_t)(b * S_ + s0)) * DI_ + d;
  const float* bp = bc + ((size_t)(b * S_ + s0)) * 32;
  float* yp = ylocal + ((size_t)(b * S_ + s0)) * DI_ + d;
  float* cp = cumd + ((size_t)(b * S_ + s0)) * DI_ + d;

  float dl_next = dp[0];
  float u_next = __bfloat162float(up[0]);
#pragma unroll 4
  for (int s = 0; s < TS; ++s) {
    float dl = dl_next, u = u_next;
    if (s + 1 < TS) {
      dl_next = dp[(size_t)(s + 1) * DI_];
      u_next = __bfloat162float(up[(size_t)(s + 1) * DI_]);
    }
    cd += dl;
    float dlu = dl * u;
    float y = 0.f;
#pragma unroll
    for (int n = 0; n < 16; ++n) {
      float e = __expf(dl * A[n]);
      hst[n] = fmaf(hst[n], e, dlu * bp[s * 32 + n]);
      y = fmaf(hst[n], bp[s * 32 + 16 + n], y);
    }
    yp[(size_t)s * DI_] = fmaf(u, Dd, y);
    cp[(size_t)s * DI_] = cd;
  }
  float* hp = hend + ((size_t)(b * NSEG + seg) * 16) * DI_ + d;
#pragma unroll
  for (int n = 0; n < 16; ++n) hp[(size_t)n * DI_] = hst[n];
}

__global__ void k_scanB(const float* __restrict__ hend, const float* __restrict__ cumd,
                        const float* __restrict__ At, float* __restrict__ h0seg) {
  int idx = blockIdx.x * 256 + threadIdx.x;
  if (idx >= B_ * 16 * DI_) return;
  int d = idx % DI_;
  int r = idx / DI_;
  int n = r & 15;
  int b = r >> 4;
  float A = At[(size_t)n * DI_ + d];
  float h0 = 0.f;
  for (int seg = 0; seg < NSEG; ++seg) {
    size_t o = ((size_t)(b * NSEG + seg) * 16 + n) * DI_ + d;
    h0seg[o] = h0;
    float cdt = cumd[((size_t)(b * S_ + seg * TS + TS - 1)) * DI_ + d];
    h0 = h0 * __expf(A * cdt) + hend[o];
  }
}

// Pass C: z comes from the SUM of the 2 bf16 inproj partials (z half)
__global__ __launch_bounds__(256)
void k_scanC(const float* __restrict__ ylocal, const float* __restrict__ cumd,
             const float* __restrict__ bc, const float* __restrict__ At,
             const float* __restrict__ h0seg, const bf16* __restrict__ pip,
             bf16* __restrict__ yb16) {
  int d = blockIdx.x * 256 + threadIdx.x;
  int t = blockIdx.y;
  int b = blockIdx.z;
  int seg = t / TS;
  size_t o = ((size_t)(b * S_ + t)) * DI_ + d;
  float y = ylocal[o];
  if (seg) {
    float cd = cumd[o];
    const float* Cp = bc + ((size_t)(b * S_ + t)) * 32 + 16;
    const float* Hb = h0seg + ((size_t)(b * NSEG + seg) * 16) * DI_ + d;
#pragma unroll
    for (int n = 0; n < 16; ++n)
      y += Cp[n] * __expf(At[(size_t)n * DI_ + d] * cd) * Hb[(size_t)n * DI_];
  }
  size_t oz = ((size_t)(b * S_ + t)) * (2 * DI_) + DI_ + d;
  float z = __bfloat162float(pip[oz]) + __bfloat162float(pip[PMN_IP + oz]);
  float sig = 1.f / (1.f + __expf(-z));
  yb16[o] = __float2bfloat16(y * (z * sig));
}

// head stage 1: block (j,b) reduces rows s in [j*32, j*32+32)
__global__ void k_head1(const bf16* __restrict__ hf, const float* __restrict__ wh,
                        float* __restrict__ partial) {
  __shared__ float red[4];
  int b = blockIdx.y, j = blockIdx.x;
  const bf16* base = hf + ((size_t)b * S_ + j * 32) * DM_;
  float acc = 0.f;
  for (int i = threadIdx.x; i < 32 * DM_; i += 256) {
    int dd = i - (i / DM_) * DM_;
    acc += __bfloat162float(base[i]) * wh[dd];
  }
  for (int off = 32; off; off >>= 1) acc += __shfl_down(acc, off);
  if ((threadIdx.x & 63) == 0) red[threadIdx.x >> 6] = acc;
  __syncthreads();
  if (threadIdx.x == 0)
    partial[b * 16 + j] = red[0] + red[1] + red[2] + red[3];
}

__global__ void k_head2(const float* __restrict__ partial, const float* __restrict__ bh,
                        float* __restrict__ out) {
  int b = threadIdx.x;
  if (b < B_) {
    float acc = 0.f;
    for (int j = 0; j < 16; ++j) acc += partial[b * 16 + j];
    out[b] = acc * (1.f / S_) + bh[0];
  }
}

// ---------------- MFMA GEMM v5 ----------------
// 128x128 tile, BK=64, double-buffered LDS, counted vmcnt(8) depth-1 prefetch,
// chunk-major conflict-free LDS layout, XCD swizzle, split-K via blockIdx.z.
// EPI: 0 f32 out; 3 bias+softplus f32; 5 split-K partial f32; 6 bf16 out;
//      7 split-K partial bf16
template <int EPI>
__global__ __launch_bounds__(256)
void k_gemm_mfma(const bf16* __restrict__ A, int lda,
                 const bf16* __restrict__ W, int ldw,
                 const float* __restrict__ bias,
                 void* __restrict__ out1,
                 int ldc, int N, int Kdim, int pmn) {
  __shared__ short As[2][8192];   // [buf][chunk(8)][row(128)][8]
  __shared__ short Bs[2][8192];

  int nwg = gridDim.x * gridDim.y;
  int orig = blockIdx.y * gridDim.x + blockIdx.x;
  int wg = (nwg % 8 == 0) ? ((orig & 7) * (nwg >> 3) + (orig >> 3)) : orig;
  int m0 = (wg / gridDim.x) * 128;
  int n0 = (wg % gridDim.x) * 128;

  int lane = threadIdx.x & 63;
  int wid = threadIdx.x >> 6;
  int wm = wid >> 1, wn = wid & 1;
  int lr = lane & 15;
  int ch = lane >> 4;
  int koff = blockIdx.z * Kdim;

  f32x4 acc[4][4];
#pragma unroll
  for (int i = 0; i < 4; ++i)
#pragma unroll
    for (int j = 0; j < 4; ++j) {
      acc[i][j][0] = 0.f; acc[i][j][1] = 0.f; acc[i][j][2] = 0.f; acc[i][j][3] = 0.f;
    }

#define GSTAGE(bb, kt)                                                            \
  {                                                                               \
    int k0 = koff + (kt) * 64;                                                    \
    _Pragma("unroll")                                                             \
    for (int c0 = 0; c0 < 4; ++c0) {                                              \
      int c = c0 * 256 + (int)threadIdx.x;                                        \
      int row = c & 127, chk = c >> 7;                                            \
      GLDS16(A + (size_t)(m0 + row) * lda + k0 + chk * 8,                         \
             (char*)&As[bb][0] + c * 16);                                         \
      GLDS16(W + (size_t)(n0 + row) * ldw + k0 + chk * 8,                         \
             (char*)&Bs[bb][0] + c * 16);                                         \
    }                                                                             \
  }

  int nt = Kdim / 64;
  GSTAGE(0, 0);

  for (int t = 0; t < nt; ++t) {
    int buf = t & 1;
    if (t + 1 < nt) {
      GSTAGE(buf ^ 1, t + 1);
      asm volatile("s_waitcnt vmcnt(8)" ::: "memory");
    } else {
      asm volatile("s_waitcnt vmcnt(0)" ::: "memory");
    }
    __builtin_amdgcn_s_barrier();
    __builtin_amdgcn_sched_barrier(0);

    short8 a0[4], a1[4], b0[4], b1[4];
#pragma unroll
    for (int f = 0; f < 4; ++f) {
      a0[f] = *(const short8*)&As[buf][(ch * 128 + wm * 64 + f * 16 + lr) * 8];
      b0[f] = *(const short8*)&Bs[buf][(ch * 128 + wn * 64 + f * 16 + lr) * 8];
    }
    __builtin_amdgcn_sched_barrier(0);
#pragma unroll
    for (int f = 0; f < 4; ++f) {
      a1[f] = *(const short8*)&As[buf][((4 + ch) * 128 + wm * 64 + f * 16 + lr) * 8];
      b1[f] = *(const short8*)&Bs[buf][((4 + ch) * 128 + wn * 64 + f * 16 + lr) * 8];
    }
    asm volatile("s_waitcnt lgkmcnt(8)" ::: "memory");
    __builtin_amdgcn_sched_barrier(0);
    __builtin_amdgcn_s_setprio(1);
#pragma unroll
    for (int i = 0; i < 4; ++i)
#pragma unroll
      for (int j = 0; j < 4; ++j)
        acc[i][j] = __builtin_amdgcn_mfma_f32_16x16x32_bf16(a0[i], b0[j], acc[i][j], 0, 0, 0);
    __builtin_amdgcn_sched_barrier(0);
    asm volatile("s_waitcnt lgkmcnt(0)" ::: "memory");
    __builtin_amdgcn_sched_barrier(0);
#pragma unroll
    for (int i = 0; i < 4; ++i)
#pragma unroll
      for (int j = 0; j < 4; ++j)
        acc[i][j] = __builtin_amdgcn_mfma_f32_16x16x32_bf16(a1[i], b1[j], acc[i][j], 0, 0, 0);
    __builtin_amdgcn_s_setprio(0);
    __builtin_amdgcn_sched_barrier(0);
    __builtin_amdgcn_s_barrier();
  }
#undef GSTAGE

#pragma unroll
  for (int i = 0; i < 4; ++i) {
#pragma unroll
    for (int j = 0; j < 4; ++j) {
      int nl = wn * 64 + j * 16 + (lane & 15);
      int n = n0 + nl;
#pragma unroll
      for (int q = 0; q < 4; ++q) {
        int m = m0 + wm * 64 + i * 16 + (lane >> 4) * 4 + q;
        float v = acc[i][j][q];
        if (EPI == 0) {
          ((float*)out1)[(size_t)m * ldc + n] = v;
        } else if (EPI == 3) {
          v += bias[n];
          v = (v > 20.f) ? v : log1pf(expf(v));
          ((float*)out1)[(size_t)m * ldc + n] = v;
        } else if (EPI == 5) {
          ((float*)out1)[(size_t)blockIdx.z * pmn + (size_t)m * N + n] = v;
        } else if (EPI == 6) {
          ((bf16*)out1)[(size_t)m * ldc + n] = __float2bfloat16(v);
        } else if (EPI == 7) {
          ((bf16*)out1)[(size_t)blockIdx.z * pmn + (size_t)m * N + n] = __float2bfloat16(v);
        }
      }
    }
  }
}

// split-K reduce for xproj: sum 8 partials, emit dtp (bf16, K-padded 64) + bc (f32)
__global__ void k_xreduce(const float* __restrict__ pxp, bf16* __restrict__ dtp,
                          float* __restrict__ bcb) {
  int idx = blockIdx.x * 256 + threadIdx.x;
  if (idx >= 2048 * 128) return;
  int m = idx >> 7, n = idx & 127;
  float s = 0.f;
#pragma unroll
  for (int k = 0; k < 8; ++k) s += pxp[(size_t)k * 2048 * 128 + idx];
  if (n < 64) dtp[m * 64 + n] = __float2bfloat16(n < 48 ? s : 0.f);
  if (n >= 48 && n < 80) bcb[m * 32 + (n - 48)] = s;
}

// ---------------- launch ----------------

extern "C" void kernel_launch(void* const* d_in, const int* in_sizes, int n_in,
                              void* d_out, int out_size, void* d_ws, size_t ws_size,
                              hipStream_t stream) {
  const float* x        = (const float*)d_in[0];
  const float* w_in     = (const float*)d_in[1];
  const float* b_in     = (const float*)d_in[2];
  const float* pe       = (const float*)d_in[3];
  const float* ln1_w    = (const float*)d_in[4];
  const float* ln1_b    = (const float*)d_in[5];
  const float* w_inproj = (const float*)d_in[6];
  const float* conv_w   = (const float*)d_in[7];
  const float* conv_b   = (const float*)d_in[8];
  const float* w_xproj  = (const float*)d_in[9];
  const float* w_dt     = (const float*)d_in[10];
  const float* b_dt     = (const float*)d_in[11];
  const float* A_log    = (const float*)d_in[12];
  const float* Dv       = (const float*)d_in[13];
  const float* w_outproj= (const float*)d_in[14];
  const float* ln2_w    = (const float*)d_in[15];
  const float* ln2_b    = (const float*)d_in[16];
  const float* ff_w1    = (const float*)d_in[17];
  const float* ff_b1    = (const float*)d_in[18];
  const float* ff_w2    = (const float*)d_in[19];
  const float* ff_b2    = (const float*)d_in[20];
  const float* lnf_w    = (const float*)d_in[21];
  const float* lnf_b    = (const float*)d_in[22];
  const float* w_head   = (const float*)d_in[23];
  const float* b_head   = (const float*)d_in[24];
  float* out = (float*)d_out;

  const int M = B_ * S_;  // 2048

  float* wsf = (float*)d_ws;
  float* h    = wsf; wsf += (size_t)M * DM_;
  float* bc   = wsf; wsf += (size_t)M * 32;
  float* dlt  = wsf; wsf += (size_t)M * DI_;
  float* cumd = wsf; wsf += (size_t)M * DI_;
  float* hend = wsf; wsf += (size_t)B_ * NSEG * DI_ * 16;
  float* h0sg = wsf; wsf += (size_t)B_ * NSEG * DI_ * 16;
  float* pxp  = wsf; wsf += (size_t)4 * M * 2 * DM_;
  float* At   = wsf; wsf += (size_t)L_ * 16 * DI_;
  float* part = wsf; wsf += 64;
  bf16* wsb = (bf16*)wsf;
  bf16* xln16 = wsb; wsb += (size_t)M * DM_;
  bf16* pip   = wsb; wsb += 2 * PMN_IP;            // inproj bf16 partials (2 chunks)
  bf16* xcb   = wsb; wsb += (size_t)M * DI_;
  bf16* dtp   = wsb; wsb += (size_t)M * 64;
  bf16* yb16  = wsb; wsb += (size_t)M * DI_;
  bf16* ffh16 = wsb; wsb += (size_t)M * DI_;
  bf16* wip   = wsb; wsb += (size_t)L_ * 2 * DI_ * DM_;
  bf16* wxp   = wsb; wsb += (size_t)L_ * 128 * DI_;
  bf16* wdtp  = wsb; wsb += (size_t)L_ * DI_ * 64;
  bf16* wop   = wsb; wsb += (size_t)L_ * DM_ * DI_;
  bf16* wf1   = wsb; wsb += (size_t)L_ * 2 * DM_ * DM_;
  bf16* wf2   = wsb; wsb += (size_t)L_ * DM_ * 2 * DM_;

  float* ylocal = dlt;          // scanA same-thread RAW alias (safe)
  bf16* pxp16 = (bf16*)pxp;     // bf16 split-K partials (ff1 / outproj / ff2)

  dim3 blk(256);

  // merged init: embed+LN1 (blocks 0..2047) + all weight casts (blocks 2048..3071)
  k_init<<<2048 + 1024, blk, 0, stream>>>(
      x, w_in, b_in, pe, ln1_w, ln1_b, h, xln16,
      w_inproj, w_outproj, ff_w1, ff_w2, w_xproj, w_dt, A_log,
      wip, wop, wf1, wf2, wxp, wdtp, At);

  for (int l = 0; l < L_; ++l) {
    const float* Atl = At + (size_t)l * 16 * DI_;

    // inproj split-K=2 -> bf16 partials pip  (M x 3072, K'=384, nt=6) [768 blocks]
    k_gemm_mfma<7><<<dim3(2 * DI_ / 128, M / 128, 2), blk, 0, stream>>>(
        xln16, DM_, wip + (size_t)l * 2 * DI_ * DM_, DM_, nullptr,
        pip, 2 * DI_, 2 * DI_, DM_ / 2, (int)PMN_IP);

    // conv + SiLU over summed partials -> xcb
    k_conv_silu<<<(B_ * S_ * (DI_ / 2) + 255) / 256, blk, 0, stream>>>(
        pip, conv_w + l * DI_ * KC_, conv_b + l * DI_, xcb);

    // xproj split-K=8 (M x 128, K'=192, nt=3) [128 blocks]
    k_gemm_mfma<5><<<dim3(1, M / 128, 8), blk, 0, stream>>>(
        xcb, DI_, wxp + (size_t)l * 128 * DI_, DI_, nullptr,
        pxp, 128, 128, DI_ / 8, M * 128);
    k_xreduce<<<(M * 128) / 256, blk, 0, stream>>>(pxp, dtp, bc);

    // delta = softplus(dtp @ wdtp^T + b_dt)   (M x 1536, K=64, nt=1) [192 blocks]
    k_gemm_mfma<3><<<dim3(DI_ / 128, M / 128), blk, 0, stream>>>(
        dtp, 64, wdtp + (size_t)l * DI_ * 64, 64, b_dt + l * DI_,
        dlt, DI_, DI_, 64, 0);

    // segmented scan (NSEG=32, TS=16)
    k_scanA<<<dim3(DI_ / 256, B_, NSEG), blk, 0, stream>>>(
        dlt, xcb, bc, Atl, Dv + l * DI_, ylocal, cumd, hend);
    k_scanB<<<(B_ * 16 * DI_ + 255) / 256, blk, 0, stream>>>(hend, cumd, Atl, h0sg);
    k_scanC<<<dim3(DI_ / 256, S_, B_), blk, 0, stream>>>(
        ylocal, cumd, bc, Atl, h0sg, pip, yb16);

    // outproj split-K=4 (M x 768, K'=384, nt=6) [384 blocks] -> bf16 partials
    k_gemm_mfma<7><<<dim3(DM_ / 128, M / 128, 4), blk, 0, stream>>>(
        yb16, DI_, wop + (size_t)l * DM_ * DI_, DI_, nullptr,
        pxp16, DM_, DM_, DI_ / 4, M * DM_);
    k_lnred<<<M, blk, 0, stream>>>(pxp16, 4, h, nullptr,
                                   ln2_w + l * DM_, ln2_b + l * DM_, h, xln16);

    // ff1 split-K=2 (M x 1536, K'=384, nt=6) [384 blocks] -> bf16 partials
    k_gemm_mfma<7><<<dim3(2 * DM_ / 128, M / 128, 2), blk, 0, stream>>>(
        xln16, DM_, wf1 + (size_t)l * 2 * DM_ * DM_, DM_, nullptr,
        pxp16, 2 * DM_, 2 * DM_, DM_ / 2, M * 2 * DM_);
    k_gelred<<<(M * 2 * DM_) / 256, blk, 0, stream>>>(pxp16, ff_b1 + l * 2 * DM_, ffh16);

    // ff2 split-K=4 (M x 768, K'=384, nt=6) [384 blocks] -> bf16 partials
    k_gemm_mfma<7><<<dim3(DM_ / 128, M / 128, 4), blk, 0, stream>>>(
        ffh16, 2 * DM_, wf2 + (size_t)l * DM_ * 2 * DM_, 2 * DM_, nullptr,
        pxp16, DM_, DM_, DI_ / 4, M * DM_);
    const float* nlw = (l + 1 < L_) ? ln1_w + (l + 1) * DM_ : lnf_w;
    const float* nlb = (l + 1 < L_) ? ln1_b + (l + 1) * DM_ : lnf_b;
    k_lnred<<<M, blk, 0, stream>>>(pxp16, 4, h, ff_b2 + l * DM_, nlw, nlb, h, xln16);
  }

  k_head1<<<dim3(16, B_), blk, 0, stream>>>(xln16, w_head, part);
  k_head2<<<1, 64, 0, stream>>>(part, b_head, out);
}

// Round 17
// 489.244 us; speedup vs baseline: 1.0931x; 1.0173x over previous
//
#include <hip/hip_runtime.h>
#include <hip/hip_bf16.h>
#include <math.h>

#define B_ 4
#define S_ 512
#define DM_ 768
#define L_ 2
#define DI_ 1536
#define DS_ 16
#define KC_ 4
#define DTR_ 48
#define NSEG 32
#define TS 16
#define PMN_IP ((size_t)2048 * 2 * DI_)   // inproj partial chunk stride (elements)

typedef __hip_bfloat16 bf16;
typedef __attribute__((ext_vector_type(8))) short short8;
typedef __attribute__((ext_vector_type(4))) float f32x4;

#define GLDS16(g, l) __builtin_amdgcn_global_load_lds( \
    (const __attribute__((address_space(1))) void*)(g), \
    (__attribute__((address_space(3))) void*)(l), 16, 0, 0)

// ---------------- vectorized cast helpers ----------------
typedef struct { unsigned short x, y, z, w; } us4;
__device__ __forceinline__ void cast4(const float* __restrict__ s, bf16* __restrict__ d) {
  float4 v = *(const float4*)s;
  us4 o;
  o.x = __bfloat16_as_ushort(__float2bfloat16(v.x));
  o.y = __bfloat16_as_ushort(__float2bfloat16(v.y));
  o.z = __bfloat16_as_ushort(__float2bfloat16(v.z));
  o.w = __bfloat16_as_ushort(__float2bfloat16(v.w));
  *(us4*)d = o;
}
__device__ __forceinline__ void store4z(bf16* __restrict__ d) {
  us4 o; o.x = o.y = o.z = o.w = 0;
  *(us4*)d = o;
}

// ---------------- merged init: embed+LN1 (blocks 0..2047) + weight casts ----------------
__global__ __launch_bounds__(256)
void k_init(const float* __restrict__ x, const float* __restrict__ w_in,
            const float* __restrict__ b_in, const float* __restrict__ pe,
            const float* __restrict__ lw, const float* __restrict__ lb,
            float* __restrict__ h, bf16* __restrict__ xout,
            const float* __restrict__ w_inproj, const float* __restrict__ w_outproj,
            const float* __restrict__ ff_w1, const float* __restrict__ ff_w2,
            const float* __restrict__ w_xproj, const float* __restrict__ w_dt,
            const float* __restrict__ A_log,
            bf16* __restrict__ wip, bf16* __restrict__ wop,
            bf16* __restrict__ wf1, bf16* __restrict__ wf2,
            bf16* __restrict__ wxp, bf16* __restrict__ wdtp,
            float* __restrict__ At, float* __restrict__ part) {
  if (blockIdx.x < 2048) {
    // ---- embed + LN1, one block per row ----
    __shared__ float red1[4], red2[4];
    __shared__ float s_mu, s_rstd;
    int row = blockIdx.x;
    int s = row % S_;
    float xv = x[row];
    float v[3];
    float s1 = 0.f, s2 = 0.f;
#pragma unroll
    for (int j = 0; j < 3; ++j) {
      int d = threadIdx.x + j * 256;
      float t = xv * w_in[d] + b_in[d] + pe[s * DM_ + d];
      v[j] = t;
      s1 += t; s2 += t * t;
    }
    for (int off = 32; off; off >>= 1) { s1 += __shfl_down(s1, off); s2 += __shfl_down(s2, off); }
    if ((threadIdx.x & 63) == 0) { red1[threadIdx.x >> 6] = s1; red2[threadIdx.x >> 6] = s2; }
    __syncthreads();
    if (threadIdx.x == 0) {
      float t1 = red1[0] + red1[1] + red1[2] + red1[3];
      float t2 = red2[0] + red2[1] + red2[2] + red2[3];
      float mu = t1 * (1.f / DM_);
      float var = t2 * (1.f / DM_) - mu * mu;
      s_mu = mu;
      s_rstd = rsqrtf(var + 1e-5f);
    }
    __syncthreads();
    float mu = s_mu, rstd = s_rstd;
#pragma unroll
    for (int j = 0; j < 3; ++j) {
      int d = threadIdx.x + j * 256;
      h[(size_t)row * DM_ + d] = v[j];
      xout[(size_t)row * DM_ + d] = __float2bfloat16((v[j] - mu) * rstd * lw[d] + lb[d]);
    }
    return;
  }
  if (blockIdx.x == 2048 && threadIdx.x < B_) part[threadIdx.x] = 0.f;
  // ---- weight casts (grid-strided over 1024 blocks) ----
  const int N0 = L_ * 2 * DI_ * DM_;
  const int N1 = L_ * DM_ * DI_;
  const int N2 = L_ * 2 * DM_ * DM_;
  const int N3 = L_ * DM_ * 2 * DM_;
  const int N4 = L_ * 128 * DI_;
  const int N5 = L_ * DI_ * 64;
  const int N6 = L_ * 16 * DI_;
  const int T4 = (N0 + N1 + N2 + N3 + N4 + N5) >> 2;
  int tid = (blockIdx.x - 2048) * 256 + threadIdx.x;
  int stride = 1024 * 256;
  for (int v = tid; v < T4; v += stride) {
    int j = v << 2;
    if (j < N0) { cast4(w_inproj + j, wip + j); continue; }
    j -= N0;
    if (j < N1) { cast4(w_outproj + j, wop + j); continue; }
    j -= N1;
    if (j < N2) { cast4(ff_w1 + j, wf1 + j); continue; }
    j -= N2;
    if (j < N3) { cast4(ff_w2 + j, wf2 + j); continue; }
    j -= N3;
    if (j < N4) {
      int col = j % DI_;
      int row = (j / DI_) & 127;
      int l = j / (128 * DI_);
      if (row < 80) cast4(&w_xproj[((size_t)l * 80 + row) * DI_ + col], wxp + j);
      else store4z(wxp + j);
      continue;
    }
    j -= N4;
    {
      int col = j & 63;
      int r = (j >> 6) % DI_;
      int l = j / (DI_ * 64);
      if (col < 48) cast4(&w_dt[((size_t)l * DI_ + r) * 48 + col], wdtp + j);
      else store4z(wdtp + j);
    }
  }
  for (int j = tid; j < N6; j += stride) {
    int d = j % DI_;
    int n = (j / DI_) & 15;
    int l = j / (16 * DI_);
    At[j] = -__expf(A_log[((size_t)l * DI_ + d) * 16 + n]);
  }
}

// fused split-K reduce (bf16 partials) + bias? + residual + LayerNorm
// + optional head-dot accumulation (wh/headp non-null on final call)
__global__ __launch_bounds__(256)
void k_lnred(const bf16* __restrict__ pxp, int KS,
             const float* __restrict__ hin, const float* __restrict__ bias,
             const float* __restrict__ lw, const float* __restrict__ lb,
             float* __restrict__ hout, bf16* __restrict__ xout,
             const float* __restrict__ wh, float* __restrict__ headp) {
  __shared__ float red1[4], red2[4];
  __shared__ float s_mu, s_rstd;
  int row = blockIdx.x;
  float v[3];
  float s1 = 0.f, s2 = 0.f;
#pragma unroll
  for (int j = 0; j < 3; ++j) {
    int n = threadIdx.x + j * 256;
    float s = hin[(size_t)row * DM_ + n];
    if (bias) s += bias[n];
    for (int ks = 0; ks < KS; ++ks)
      s += __bfloat162float(pxp[(size_t)ks * 2048 * DM_ + (size_t)row * DM_ + n]);
    v[j] = s;
    s1 += s; s2 += s * s;
  }
  for (int off = 32; off; off >>= 1) { s1 += __shfl_down(s1, off); s2 += __shfl_down(s2, off); }
  if ((threadIdx.x & 63) == 0) { red1[threadIdx.x >> 6] = s1; red2[threadIdx.x >> 6] = s2; }
  __syncthreads();
  if (threadIdx.x == 0) {
    float t1 = red1[0] + red1[1] + red1[2] + red1[3];
    float t2 = red2[0] + red2[1] + red2[2] + red2[3];
    float mu = t1 * (1.f / DM_);
    float var = t2 * (1.f / DM_) - mu * mu;
    s_mu = mu;
    s_rstd = rsqrtf(var + 1e-5f);
  }
  __syncthreads();
  float mu = s_mu, rstd = s_rstd;
  float hacc = 0.f;
#pragma unroll
  for (int j = 0; j < 3; ++j) {
    int n = threadIdx.x + j * 256;
    float vl = (v[j] - mu) * rstd * lw[n] + lb[n];
    hout[(size_t)row * DM_ + n] = v[j];
    xout[(size_t)row * DM_ + n] = __float2bfloat16(vl);
    if (headp) hacc += vl * wh[n];
  }
  if (headp) {
    __syncthreads();
    for (int off = 32; off; off >>= 1) hacc += __shfl_down(hacc, off);
    if ((threadIdx.x & 63) == 0) red1[threadIdx.x >> 6] = hacc;
    __syncthreads();
    if (threadIdx.x == 0)
      atomicAdd(headp + row / S_, red1[0] + red1[1] + red1[2] + red1[3]);
  }
}

// fused split-K(2) reduce (bf16 partials) + bias + exact GELU -> bf16 (ff1 epilogue)
__global__ void k_gelred(const bf16* __restrict__ pxp, const float* __restrict__ bias,
                         bf16* __restrict__ out) {
  int idx = blockIdx.x * 256 + threadIdx.x;
  if (idx >= 2048 * 2 * DM_) return;
  int n = idx % (2 * DM_);
  float s = __bfloat162float(pxp[idx]) +
            __bfloat162float(pxp[(size_t)2048 * 2 * DM_ + idx]) + bias[n];
  s = 0.5f * s * (1.f + erff(s * 0.70710678118654752f));
  out[idx] = __float2bfloat16(s);
}

// depthwise causal conv (K=4) + bias + SiLU over SUM of 2 bf16 inproj partials;
// 2 d's per thread, ushort2 loads/stores
__global__ void k_conv_silu(const bf16* __restrict__ pip, const float* __restrict__ cw,
                            const float* __restrict__ cb, bf16* __restrict__ xcb) {
  int idx = blockIdx.x * 256 + threadIdx.x;
  if (idx >= B_ * S_ * (DI_ / 2)) return;
  int d2 = idx % (DI_ / 2);
  int d = d2 * 2;
  int t = idx / (DI_ / 2);
  int s = t % S_;
  int b = t / S_;
  float a0 = cb[d], a1 = cb[d + 1];
  const bf16* p0 = pip + (size_t)(b * S_) * (2 * DI_) + d;
  const bf16* p1 = p0 + PMN_IP;
#pragma unroll
  for (int k = 0; k < KC_; ++k) {
    int ss = s - (KC_ - 1) + k;
    if (ss >= 0) {
      ushort2 u0 = *(const ushort2*)&p0[(size_t)ss * (2 * DI_)];
      ushort2 u1 = *(const ushort2*)&p1[(size_t)ss * (2 * DI_)];
      float x0 = __bfloat162float(__ushort_as_bfloat16(u0.x)) +
                 __bfloat162float(__ushort_as_bfloat16(u1.x));
      float x1 = __bfloat162float(__ushort_as_bfloat16(u0.y)) +
                 __bfloat162float(__ushort_as_bfloat16(u1.y));
      a0 = fmaf(x0, cw[d * KC_ + k], a0);
      a1 = fmaf(x1, cw[(d + 1) * KC_ + k], a1);
    }
  }
  float v0 = a0 / (1.f + expf(-a0));
  float v1 = a1 / (1.f + expf(-a1));
  ushort2 o;
  o.x = __bfloat16_as_ushort(__float2bfloat16(v0));
  o.y = __bfloat16_as_ushort(__float2bfloat16(v1));
  *(ushort2*)&xcb[(size_t)t * DI_ + d] = o;
}

// ---------------- segmented selective scan ----------------
// Pass A v3: fuses the Delta-projection. Per thread (one d): w_dt[d][0..47] in
// VGPRs; dtp rows are block-uniform -> read as uniform dwords (SGPR path),
// bf16 halves unpacked by shift/mask; delta = softplus(b_dt + dot48) inline.
__global__ __launch_bounds__(256)
void k_scanA(const bf16* __restrict__ dtp, const bf16* __restrict__ wdt_l,
             const float* __restrict__ bdt_l,
             const bf16* __restrict__ xcb, const float* __restrict__ bc,
             const float* __restrict__ At, const float* __restrict__ Dv,
             float* __restrict__ ylocal, float* __restrict__ cumd,
             float* __restrict__ hend) {
  int b = blockIdx.y;
  int seg = blockIdx.z;
  int d = blockIdx.x * 256 + threadIdx.x;
  int s0 = seg * TS;

  float A[16], hst[16];
#pragma unroll
  for (int n = 0; n < 16; ++n) {
    A[n] = At[(size_t)n * DI_ + d];
    hst[n] = 0.f;
  }
  float wdt[48];
  {
    const bf16* wrow = wdt_l + (size_t)d * 64;
#pragma unroll
    for (int k = 0; k < 48; ++k) wdt[k] = __bfloat162float(wrow[k]);
  }
  float bdt = bdt_l[d];
  float Dd = Dv[d];
  float cd = 0.f;

  const unsigned int* dru = (const unsigned int*)(dtp) + (size_t)(b * S_ + s0) * 32;
  const bf16* up = xcb + ((size_t)(b * S_ + s0)) * DI_ + d;
  const float* bp = bc + ((size_t)(b * S_ + s0)) * 32;
  float* yp = ylocal + ((size_t)(b * S_ + s0)) * DI_ + d;
  float* cp = cumd + ((size_t)(b * S_ + s0)) * DI_ + d;

  float u_next = __bfloat162float(up[0]);
#pragma unroll 4
  for (int s = 0; s < TS; ++s) {
    float u = u_next;
    if (s + 1 < TS) u_next = __bfloat162float(up[(size_t)(s + 1) * DI_]);
    // delta = softplus(bdt + dot48(dtp[row], wdt)) — dtp row is block-uniform
    float acc = bdt;
#pragma unroll
    for (int kk = 0; kk < 24; ++kk) {
      unsigned int w2 = dru[s * 32 + kk];
      acc = fmaf(__uint_as_float(w2 << 16), wdt[2 * kk], acc);
      acc = fmaf(__uint_as_float(w2 & 0xffff0000u), wdt[2 * kk + 1], acc);
    }
    float dl = (acc > 20.f) ? acc : log1pf(__expf(acc));
    cd += dl;
    float dlu = dl * u;
    float y = 0.f;
#pragma unroll
    for (int n = 0; n < 16; ++n) {
      float e = __expf(dl * A[n]);
      hst[n] = fmaf(hst[n], e, dlu * bp[s * 32 + n]);
      y = fmaf(hst[n], bp[s * 32 + 16 + n], y);
    }
    yp[(size_t)s * DI_] = fmaf(u, Dd, y);
    cp[(size_t)s * DI_] = cd;
  }
  float* hp = hend + ((size_t)(b * NSEG + seg) * 16) * DI_ + d;
#pragma unroll
  for (int n = 0; n < 16; ++n) hp[(size_t)n * DI_] = hst[n];
}

__global__ void k_scanB(const float* __restrict__ hend, const float* __restrict__ cumd,
                        const float* __restrict__ At, float* __restrict__ h0seg) {
  int idx = blockIdx.x * 256 + threadIdx.x;
  if (idx >= B_ * 16 * DI_) return;
  int d = idx % DI_;
  int r = idx / DI_;
  int n = r & 15;
  int b = r >> 4;
  float A = At[(size_t)n * DI_ + d];
  float h0 = 0.f;
  for (int seg = 0; seg < NSEG; ++seg) {
    size_t o = ((size_t)(b * NSEG + seg) * 16 + n) * DI_ + d;
    h0seg[o] = h0;
    float cdt = cumd[((size_t)(b * S_ + seg * TS + TS - 1)) * DI_ + d];
    h0 = h0 * __expf(A * cdt) + hend[o];
  }
}

// Pass C: z comes from the SUM of the 2 bf16 inproj partials (z half)
__global__ __launch_bounds__(256)
void k_scanC(const float* __restrict__ ylocal, const float* __restrict__ cumd,
             const float* __restrict__ bc, const float* __restrict__ At,
             const float* __restrict__ h0seg, const bf16* __restrict__ pip,
             bf16* __restrict__ yb16) {
  int d = blockIdx.x * 256 + threadIdx.x;
  int t = blockIdx.y;
  int b = blockIdx.z;
  int seg = t / TS;
  size_t o = ((size_t)(b * S_ + t)) * DI_ + d;
  float y = ylocal[o];
  if (seg) {
    float cd = cumd[o];
    const float* Cp = bc + ((size_t)(b * S_ + t)) * 32 + 16;
    const float* Hb = h0seg + ((size_t)(b * NSEG + seg) * 16) * DI_ + d;
#pragma unroll
    for (int n = 0; n < 16; ++n)
      y += Cp[n] * __expf(At[(size_t)n * DI_ + d] * cd) * Hb[(size_t)n * DI_];
  }
  size_t oz = ((size_t)(b * S_ + t)) * (2 * DI_) + DI_ + d;
  float z = __bfloat162float(pip[oz]) + __bfloat162float(pip[PMN_IP + oz]);
  float sig = 1.f / (1.f + __expf(-z));
  yb16[o] = __float2bfloat16(y * (z * sig));
}

// head stage 2: part[b] already holds sum over (s,d); scale + bias
__global__ void k_head2(const float* __restrict__ part, const float* __restrict__ bh,
                        float* __restrict__ out) {
  int b = threadIdx.x;
  if (b < B_) out[b] = part[b] * (1.f / S_) + bh[0];
}

// ---------------- MFMA GEMM v5 ----------------
// 128x128 tile, BK=64, double-buffered LDS, counted vmcnt(8) depth-1 prefetch,
// chunk-major conflict-free LDS layout, XCD swizzle, split-K via blockIdx.z.
// EPI: 0 f32 out; 3 bias+softplus f32; 5 split-K partial f32; 6 bf16 out;
//      7 split-K partial bf16
template <int EPI>
__global__ __launch_bounds__(256)
void k_gemm_mfma(const bf16* __restrict__ A, int lda,
                 const bf16* __restrict__ W, int ldw,
                 const float* __restrict__ bias,
                 void* __restrict__ out1,
                 int ldc, int N, int Kdim, int pmn) {
  __shared__ short As[2][8192];   // [buf][chunk(8)][row(128)][8]
  __shared__ short Bs[2][8192];

  int nwg = gridDim.x * gridDim.y;
  int orig = blockIdx.y * gridDim.x + blockIdx.x;
  int wg = (nwg % 8 == 0) ? ((orig & 7) * (nwg >> 3) + (orig >> 3)) : orig;
  int m0 = (wg / gridDim.x) * 128;
  int n0 = (wg % gridDim.x) * 128;

  int lane = threadIdx.x & 63;
  int wid = threadIdx.x >> 6;
  int wm = wid >> 1, wn = wid & 1;
  int lr = lane & 15;
  int ch = lane >> 4;
  int koff = blockIdx.z * Kdim;

  f32x4 acc[4][4];
#pragma unroll
  for (int i = 0; i < 4; ++i)
#pragma unroll
    for (int j = 0; j < 4; ++j) {
      acc[i][j][0] = 0.f; acc[i][j][1] = 0.f; acc[i][j][2] = 0.f; acc[i][j][3] = 0.f;
    }

#define GSTAGE(bb, kt)                                                            \
  {                                                                               \
    int k0 = koff + (kt) * 64;                                                    \
    _Pragma("unroll")                                                             \
    for (int c0 = 0; c0 < 4; ++c0) {                                              \
      int c = c0 * 256 + (int)threadIdx.x;                                        \
      int row = c & 127, chk = c >> 7;                                            \
      GLDS16(A + (size_t)(m0 + row) * lda + k0 + chk * 8,                         \
             (char*)&As[bb][0] + c * 16);                                         \
      GLDS16(W + (size_t)(n0 + row) * ldw + k0 + chk * 8,                         \
             (char*)&Bs[bb][0] + c * 16);                                         \
    }                                                                             \
  }

  int nt = Kdim / 64;
  GSTAGE(0, 0);

  for (int t = 0; t < nt; ++t) {
    int buf = t & 1;
    if (t + 1 < nt) {
      GSTAGE(buf ^ 1, t + 1);
      asm volatile("s_waitcnt vmcnt(8)" ::: "memory");
    } else {
      asm volatile("s_waitcnt vmcnt(0)" ::: "memory");
    }
    __builtin_amdgcn_s_barrier();
    __builtin_amdgcn_sched_barrier(0);

    short8 a0[4], a1[4], b0[4], b1[4];
#pragma unroll
    for (int f = 0; f < 4; ++f) {
      a0[f] = *(const short8*)&As[buf][(ch * 128 + wm * 64 + f * 16 + lr) * 8];
      b0[f] = *(const short8*)&Bs[buf][(ch * 128 + wn * 64 + f * 16 + lr) * 8];
    }
    __builtin_amdgcn_sched_barrier(0);
#pragma unroll
    for (int f = 0; f < 4; ++f) {
      a1[f] = *(const short8*)&As[buf][((4 + ch) * 128 + wm * 64 + f * 16 + lr) * 8];
      b1[f] = *(const short8*)&Bs[buf][((4 + ch) * 128 + wn * 64 + f * 16 + lr) * 8];
    }
    asm volatile("s_waitcnt lgkmcnt(8)" ::: "memory");
    __builtin_amdgcn_sched_barrier(0);
    __builtin_amdgcn_s_setprio(1);
#pragma unroll
    for (int i = 0; i < 4; ++i)
#pragma unroll
      for (int j = 0; j < 4; ++j)
        acc[i][j] = __builtin_amdgcn_mfma_f32_16x16x32_bf16(a0[i], b0[j], acc[i][j], 0, 0, 0);
    __builtin_amdgcn_sched_barrier(0);
    asm volatile("s_waitcnt lgkmcnt(0)" ::: "memory");
    __builtin_amdgcn_sched_barrier(0);
#pragma unroll
    for (int i = 0; i < 4; ++i)
#pragma unroll
      for (int j = 0; j < 4; ++j)
        acc[i][j] = __builtin_amdgcn_mfma_f32_16x16x32_bf16(a1[i], b1[j], acc[i][j], 0, 0, 0);
    __builtin_amdgcn_s_setprio(0);
    __builtin_amdgcn_sched_barrier(0);
    __builtin_amdgcn_s_barrier();
  }
#undef GSTAGE

#pragma unroll
  for (int i = 0; i < 4; ++i) {
#pragma unroll
    for (int j = 0; j < 4; ++j) {
      int nl = wn * 64 + j * 16 + (lane & 15);
      int n = n0 + nl;
#pragma unroll
      for (int q = 0; q < 4; ++q) {
        int m = m0 + wm * 64 + i * 16 + (lane >> 4) * 4 + q;
        float v = acc[i][j][q];
        if (EPI == 0) {
          ((float*)out1)[(size_t)m * ldc + n] = v;
        } else if (EPI == 3) {
          v += bias[n];
          v = (v > 20.f) ? v : log1pf(expf(v));
          ((float*)out1)[(size_t)m * ldc + n] = v;
        } else if (EPI == 5) {
          ((float*)out1)[(size_t)blockIdx.z * pmn + (size_t)m * N + n] = v;
        } else if (EPI == 6) {
          ((bf16*)out1)[(size_t)m * ldc + n] = __float2bfloat16(v);
        } else if (EPI == 7) {
          ((bf16*)out1)[(size_t)blockIdx.z * pmn + (size_t)m * N + n] = __float2bfloat16(v);
        }
      }
    }
  }
}

// split-K reduce for xproj: sum 8 partials, emit dtp (bf16, K-padded 64) + bc (f32)
__global__ void k_xreduce(const float* __restrict__ pxp, bf16* __restrict__ dtp,
                          float* __restrict__ bcb) {
  int idx = blockIdx.x * 256 + threadIdx.x;
  if (idx >= 2048 * 128) return;
  int m = idx >> 7, n = idx & 127;
  float s = 0.f;
#pragma unroll
  for (int k = 0; k < 8; ++k) s += pxp[(size_t)k * 2048 * 128 + idx];
  if (n < 64) dtp[m * 64 + n] = __float2bfloat16(n < 48 ? s : 0.f);
  if (n >= 48 && n < 80) bcb[m * 32 + (n - 48)] = s;
}

// ---------------- launch ----------------

extern "C" void kernel_launch(void* const* d_in, const int* in_sizes, int n_in,
                              void* d_out, int out_size, void* d_ws, size_t ws_size,
                              hipStream_t stream) {
  const float* x        = (const float*)d_in[0];
  const float* w_in     = (const float*)d_in[1];
  const float* b_in     = (const float*)d_in[2];
  const float* pe       = (const float*)d_in[3];
  const float* ln1_w    = (const float*)d_in[4];
  const float* ln1_b    = (const float*)d_in[5];
  const float* w_inproj = (const float*)d_in[6];
  const float* conv_w   = (const float*)d_in[7];
  const float* conv_b   = (const float*)d_in[8];
  const float* w_xproj  = (const float*)d_in[9];
  const float* w_dt     = (const float*)d_in[10];
  const float* b_dt     = (const float*)d_in[11];
  const float* A_log    = (const float*)d_in[12];
  const float* Dv       = (const float*)d_in[13];
  const float* w_outproj= (const float*)d_in[14];
  const float* ln2_w    = (const float*)d_in[15];
  const float* ln2_b    = (const float*)d_in[16];
  const float* ff_w1    = (const float*)d_in[17];
  const float* ff_b1    = (const float*)d_in[18];
  const float* ff_w2    = (const float*)d_in[19];
  const float* ff_b2    = (const float*)d_in[20];
  const float* lnf_w    = (const float*)d_in[21];
  const float* lnf_b    = (const float*)d_in[22];
  const float* w_head   = (const float*)d_in[23];
  const float* b_head   = (const float*)d_in[24];
  float* out = (float*)d_out;

  const int M = B_ * S_;  // 2048

  float* wsf = (float*)d_ws;
  float* h    = wsf; wsf += (size_t)M * DM_;
  float* bc   = wsf; wsf += (size_t)M * 32;
  float* ylocal = wsf; wsf += (size_t)M * DI_;
  float* cumd = wsf; wsf += (size_t)M * DI_;
  float* hend = wsf; wsf += (size_t)B_ * NSEG * DI_ * 16;
  float* h0sg = wsf; wsf += (size_t)B_ * NSEG * DI_ * 16;
  float* pxp  = wsf; wsf += (size_t)4 * M * 2 * DM_;
  float* At   = wsf; wsf += (size_t)L_ * 16 * DI_;
  float* part = wsf; wsf += 64;
  bf16* wsb = (bf16*)wsf;
  bf16* xln16 = wsb; wsb += (size_t)M * DM_;
  bf16* pip   = wsb; wsb += 2 * PMN_IP;            // inproj bf16 partials (2 chunks)
  bf16* xcb   = wsb; wsb += (size_t)M * DI_;
  bf16* dtp   = wsb; wsb += (size_t)M * 64;
  bf16* yb16  = wsb; wsb += (size_t)M * DI_;
  bf16* ffh16 = wsb; wsb += (size_t)M * DI_;
  bf16* wip   = wsb; wsb += (size_t)L_ * 2 * DI_ * DM_;
  bf16* wxp   = wsb; wsb += (size_t)L_ * 128 * DI_;
  bf16* wdtp  = wsb; wsb += (size_t)L_ * DI_ * 64;
  bf16* wop   = wsb; wsb += (size_t)L_ * DM_ * DI_;
  bf16* wf1   = wsb; wsb += (size_t)L_ * 2 * DM_ * DM_;
  bf16* wf2   = wsb; wsb += (size_t)L_ * DM_ * 2 * DM_;

  bf16* pxp16 = (bf16*)pxp;     // bf16 split-K partials (ff1 / outproj / ff2)

  dim3 blk(256);

  // merged init: embed+LN1 (blocks 0..2047) + weight casts + part zero
  k_init<<<2048 + 1024, blk, 0, stream>>>(
      x, w_in, b_in, pe, ln1_w, ln1_b, h, xln16,
      w_inproj, w_outproj, ff_w1, ff_w2, w_xproj, w_dt, A_log,
      wip, wop, wf1, wf2, wxp, wdtp, At, part);

  for (int l = 0; l < L_; ++l) {
    const float* Atl = At + (size_t)l * 16 * DI_;

    // inproj split-K=2 -> bf16 partials pip  (M x 3072, K'=384, nt=6) [768 blocks]
    k_gemm_mfma<7><<<dim3(2 * DI_ / 128, M / 128, 2), blk, 0, stream>>>(
        xln16, DM_, wip + (size_t)l * 2 * DI_ * DM_, DM_, nullptr,
        pip, 2 * DI_, 2 * DI_, DM_ / 2, (int)PMN_IP);

    // conv + SiLU over summed partials -> xcb
    k_conv_silu<<<(B_ * S_ * (DI_ / 2) + 255) / 256, blk, 0, stream>>>(
        pip, conv_w + l * DI_ * KC_, conv_b + l * DI_, xcb);

    // xproj split-K=8 (M x 128, K'=192, nt=3) [128 blocks]
    k_gemm_mfma<5><<<dim3(1, M / 128, 8), blk, 0, stream>>>(
        xcb, DI_, wxp + (size_t)l * 128 * DI_, DI_, nullptr,
        pxp, 128, 128, DI_ / 8, M * 128);
    k_xreduce<<<(M * 128) / 256, blk, 0, stream>>>(pxp, dtp, bc);

    // segmented scan (NSEG=32, TS=16); Delta-projection fused into scanA
    k_scanA<<<dim3(DI_ / 256, B_, NSEG), blk, 0, stream>>>(
        dtp, wdtp + (size_t)l * DI_ * 64, b_dt + l * DI_,
        xcb, bc, Atl, Dv + l * DI_, ylocal, cumd, hend);
    k_scanB<<<(B_ * 16 * DI_ + 255) / 256, blk, 0, stream>>>(hend, cumd, Atl, h0sg);
    k_scanC<<<dim3(DI_ / 256, S_, B_), blk, 0, stream>>>(
        ylocal, cumd, bc, Atl, h0sg, pip, yb16);

    // outproj split-K=4 (M x 768, K'=384, nt=6) [384 blocks] -> bf16 partials
    k_gemm_mfma<7><<<dim3(DM_ / 128, M / 128, 4), blk, 0, stream>>>(
        yb16, DI_, wop + (size_t)l * DM_ * DI_, DI_, nullptr,
        pxp16, DM_, DM_, DI_ / 4, M * DM_);
    k_lnred<<<M, blk, 0, stream>>>(pxp16, 4, h, nullptr,
                                   ln2_w + l * DM_, ln2_b + l * DM_, h, xln16,
                                   nullptr, nullptr);

    // ff1 split-K=2 (M x 1536, K'=384, nt=6) [384 blocks] -> bf16 partials
    k_gemm_mfma<7><<<dim3(2 * DM_ / 128, M / 128, 2), blk, 0, stream>>>(
        xln16, DM_, wf1 + (size_t)l * 2 * DM_ * DM_, DM_, nullptr,
        pxp16, 2 * DM_, 2 * DM_, DM_ / 2, M * 2 * DM_);
    k_gelred<<<(M * 2 * DM_) / 256, blk, 0, stream>>>(pxp16, ff_b1 + l * 2 * DM_, ffh16);

    // ff2 split-K=4 (M x 768, K'=384, nt=6) [384 blocks] -> bf16 partials
    k_gemm_mfma<7><<<dim3(DM_ / 128, M / 128, 4), blk, 0, stream>>>(
        ffh16, 2 * DM_, wf2 + (size_t)l * DM_ * 2 * DM_, 2 * DM_, nullptr,
        pxp16, DM_, DM_, DI_ / 4, M * DM_);
    const float* nlw = (l + 1 < L_) ? ln1_w + (l + 1) * DM_ : lnf_w;
    const float* nlb = (l + 1 < L_) ? ln1_b + (l + 1) * DM_ : lnf_b;
    // final layer: fuse head stage-1 (dot with w_head, atomicAdd into part)
    const float* whp = (l + 1 < L_) ? nullptr : w_head;
    float* hpp = (l + 1 < L_) ? nullptr : part;
    k_lnred<<<M, blk, 0, stream>>>(pxp16, 4, h, ff_b2 + l * DM_, nlw, nlb, h, xln16,
                                   whp, hpp);
  }

  k_head2<<<1, 64, 0, stream>>>(part, b_head, out);
}